// Round 14
// baseline (6375.718 us; speedup 1.0000x reference)
//
#include <hip/hip_runtime.h>

// WaveNet decoder for MI355X (gfx950) — round-13 bodies (best 3.11ms), with
// dil+ressk in ONE launch per layer via BLOCK-ROLE SPLIT (not phase chaining):
//   grid 1792 = 1024 dil blocks (bid<1024: mt=bid>>7,nt=bid&127) + 768 ressk
//   blocks (bid-1024: mt'=.. rk). Each block runs exactly one body -> no
//   register-allocation merge (round-11's failure). launch_bounds(256,4)
//   guarantees capacity 1024 >= 768 spinners -> deadlock-free under any
//   dispatch order. pre_cnt[nt] flags (release: fence+atomic, acquire: spin).
//   All inter-layer state fp16 (h ping/pong, skip).

typedef _Float16 f16x8 __attribute__((ext_vector_type(8)));
typedef float f32x4 __attribute__((ext_vector_type(4)));

#define NSTACK 30
#define TLEN   16384

typedef __attribute__((address_space(1))) const unsigned int glob_u32;
typedef __attribute__((address_space(3))) unsigned int lds_u32;

__device__ __forceinline__ void gll16(const unsigned short* g, unsigned short* l) {
  __builtin_amdgcn_global_load_lds((glob_u32*)g, (lds_u32*)l, 16, 0, 0);
}

__device__ __forceinline__ unsigned short f2h(float x) {
  union { _Float16 h; unsigned short u; } c;
  c.h = (_Float16)x;
  return c.u;
}
__device__ __forceinline__ unsigned pack2(float a, float b) {
  return (unsigned)f2h(a) | ((unsigned)f2h(b) << 16);
}
__device__ __forceinline__ float uplo(unsigned u){ union{unsigned v;_Float16 h[2];}c; c.v=u; return (float)c.h[0]; }
__device__ __forceinline__ float uphi(unsigned u){ union{unsigned v;_Float16 h[2];}c; c.v=u; return (float)c.h[1]; }
__device__ __forceinline__ f16x8 ldh(const unsigned short* p) {
  return *(const f16x8*)p;
}
__device__ __forceinline__ float sigmoidf_(float x){ return 1.0f/(1.0f+__expf(-x)); }
__device__ __forceinline__ float tanhf_(float x){ return 1.0f - 2.0f/(__expf(2.0f*x)+1.0f); }
#define MFMA16(a,b,c) __builtin_amdgcn_mfma_f32_16x16x32_f16((a),(b),(c),0,0,0)

__device__ __forceinline__ void spin_ge(int* p, int v){
  while (__hip_atomic_load(p, __ATOMIC_ACQUIRE, __HIP_MEMORY_SCOPE_AGENT) < v)
    __builtin_amdgcn_s_sleep(2);
}
__device__ __forceinline__ void flag_add(int* p){
  __hip_atomic_fetch_add(p, 1, __ATOMIC_RELEASE, __HIP_MEMORY_SCOPE_AGENT);
}

// ---------------- small prep kernels ----------------

__global__ void cast_f16_kernel(const float* __restrict__ src,
                                unsigned short* __restrict__ dst, int n4) {
  int g = blockIdx.x*256 + threadIdx.x;
  if (g >= n4) return;
  f32x4 v = *(const f32x4*)(src + 4*(size_t)g);
  unsigned int* d = (unsigned int*)(dst + 4*(size_t)g);
  d[0] = pack2(v[0], v[1]);
  d[1] = pack2(v[2], v[3]);
}

// w_dil [30][1024][512][3] f32 -> A_dil [30][3][1024][512] fp16
__global__ void transpose_wdil_kernel(const float* __restrict__ src,
                                      unsigned short* __restrict__ dst) {
  int g = blockIdx.x*256 + threadIdx.x;
  if (g >= NSTACK*1024*512) return;
  int c = g & 511;
  int m = (g >> 9) & 1023;
  int i = g >> 19;
  const float* s = src + (size_t)g*3;
  #pragma unroll
  for (int tap=0; tap<3; ++tap)
    dst[(((size_t)i*3+tap)*1024 + m)*512 + c] = f2h(s[tap]);
}

// cond_all[i][m][e], fcond_all[m][e]
__global__ void cond_kernel(const float* __restrict__ emb,
                            const float* __restrict__ w_cond, const float* __restrict__ b_cond,
                            const float* __restrict__ b_dil,
                            const float* __restrict__ w_fcond, const float* __restrict__ b_fcond,
                            float* __restrict__ cond_all, float* __restrict__ fcond_all) {
  int g = blockIdx.x*256 + threadIdx.x;
  if (g < NSTACK*1024) {
    float acc[32];
    float base = b_cond[g] + b_dil[g];
    #pragma unroll
    for (int e=0;e<32;++e) acc[e] = base;
    #pragma unroll
    for (int c=0;c<16;++c) {
      float wv = w_cond[(size_t)g*16 + c];
      #pragma unroll
      for (int e=0;e<32;++e) acc[e] += wv * emb[c*32+e];
    }
    #pragma unroll
    for (int e=0;e<32;++e) cond_all[(size_t)g*32+e] = acc[e];
  } else if (g < NSTACK*1024 + 256) {
    int m = g - NSTACK*1024;
    float acc[32];
    float base = b_fcond[m];
    #pragma unroll
    for (int e=0;e<32;++e) acc[e] = base;
    #pragma unroll
    for (int c=0;c<16;++c) {
      float wv = w_fcond[(size_t)m*16 + c];
      #pragma unroll
      for (int e=0;e<32;++e) acc[e] += wv * emb[c*32+e];
    }
    #pragma unroll
    for (int e=0;e<32;++e) fcond_all[(size_t)m*32+e] = acc[e];
  }
}

// h0[t][c] = causal k3 conv of x + b_init -> fp16 ping.
__global__ void h0_kernel(const float* __restrict__ x, const float* __restrict__ w_init,
                          const float* __restrict__ b_init,
                          unsigned short* __restrict__ h_h16) {
  int g = blockIdx.x*256 + threadIdx.x;
  int t = g >> 7;
  int c = (g & 127) << 2;
  float xm2 = (t>=2)? x[t-2] : 0.f;
  float xm1 = (t>=1)? x[t-1] : 0.f;
  float x0  = x[t];
  float hv[4];
  #pragma unroll
  for (int r=0;r<4;++r) {
    int cc = c + r;
    hv[r] = w_init[cc*3+0]*xm2 + w_init[cc*3+1]*xm1 + w_init[cc*3+2]*x0 + b_init[cc];
  }
  unsigned int* hb = (unsigned int*)&h_h16[(size_t)t*512 + c];
  hb[0] = pack2(hv[0],hv[1]); hb[1] = pack2(hv[2],hv[3]);
}

// skip16[t][s] = fp16(W_iskip @ h0 + b_iskip)
__global__ __launch_bounds__(512) void skip_init_kernel(
    const unsigned short* __restrict__ h_h16, const unsigned short* __restrict__ Wiskip,
    const float* __restrict__ b_iskip, unsigned short* __restrict__ skip16) {
  int tid=threadIdx.x, w=tid>>6, l=tid&63, lr=l&15, lc=l>>4;
  int tb = blockIdx.x<<6;
  f32x4 acc[2][4];
  #pragma unroll
  for (int mf=0;mf<2;++mf)
    #pragma unroll
    for (int nf=0;nf<4;++nf) acc[mf][nf] = {0.f,0.f,0.f,0.f};
  for (int kc=0;kc<512;kc+=32) {
    f16x8 b[4];
    #pragma unroll
    for (int nf=0;nf<4;++nf)
      b[nf] = ldh(&h_h16[(size_t)(tb+16*nf+lr)*512 + kc + lc*8]);
    #pragma unroll
    for (int mf=0;mf<2;++mf) {
      f16x8 a = ldh(&Wiskip[(size_t)(w*32+16*mf+lr)*512 + kc + lc*8]);
      #pragma unroll
      for (int nf=0;nf<4;++nf)
        acc[mf][nf] = MFMA16(a, b[nf], acc[mf][nf]);
    }
  }
  #pragma unroll
  for (int mf=0;mf<2;++mf)
    #pragma unroll
    for (int nf=0;nf<4;++nf) {
      int s0 = w*32+16*mf+4*lc;
      int t  = tb+16*nf+lr;
      unsigned int* pp = (unsigned int*)&skip16[(size_t)t*256+s0];
      pp[0] = pack2(acc[mf][nf][0]+b_iskip[s0+0], acc[mf][nf][1]+b_iskip[s0+1]);
      pp[1] = pack2(acc[mf][nf][2]+b_iskip[s0+2], acc[mf][nf][3]+b_iskip[s0+3]);
    }
}

// ---------------- fused per-layer kernel (block-role split) ----------------
// grid 1792. bid<1024: dil role (nt=bid&127, mt=bid>>7). bid>=1024: ressk
// role (b2=bid-1024: nt=b2&127, rk=b2>>7 in 0..5).
__global__ __launch_bounds__(256, 4) void layer_kernel(
    const unsigned short* __restrict__ h_in,    // [T][512] fp16 ping
    unsigned short* __restrict__ h_out,         // [T][512] fp16 pong
    unsigned short* __restrict__ pre,           // [T][512] fp16
    unsigned short* __restrict__ skip16,        // [T][256] fp16 (RMW)
    const unsigned short* __restrict__ A_dil,   // [3][1024][512] fp16
    const unsigned short* __restrict__ Wres,    // [512][512] fp16
    const unsigned short* __restrict__ Wskip,   // [256][512] fp16
    const float* __restrict__ cond,             // [1024][32]
    const float* __restrict__ b_res,
    const float* __restrict__ b_skip,
    const unsigned short* __restrict__ zerobuf, // zeros
    int dilation,
    int* __restrict__ pre_cnt) {                // [128], zeroed per call
  __shared__ unsigned short Ab[2][128][32];
  __shared__ unsigned short Bb[2][128][32];
  const int tid = threadIdx.x;
  const int w = tid >> 6, l = tid & 63;
  const int lr = l & 15, lc = l >> 4;
  const int wr = w >> 1, wc = w & 1;
  const int srowA0 = (w<<5) + (l>>2);
  const int schunk = (l & 3) << 3;

  if (blockIdx.x < 1024) {
    // ================= dil role =================
    const int nt = blockIdx.x & 127, mt = blockIdx.x >> 7;
    const int tb = nt << 7;
    const int e  = tb >> 9;

    f32x4 fa[2][4], ga[2][4];
    #pragma unroll
    for (int mf=0;mf<2;++mf)
      #pragma unroll
      for (int nf=0;nf<4;++nf) { fa[mf][nf] = {0.f,0.f,0.f,0.f}; ga[mf][nf] = {0.f,0.f,0.f,0.f}; }

    auto stage = [&](int buf, int s){
      const int tap = s >> 4;
      const int kc  = (s & 15) << 5;
      const int shift = (2 - tap) * dilation;
      const unsigned short* Abase = A_dil + (size_t)tap * (1024*512) + kc + schunk;
      #pragma unroll
      for (int j=0;j<2;++j){
        const int r = srowA0 + (j<<4);
        const int m = mt*64 + r + ((r>>6)*448);  // r<64: filter ; r>=64: gate+512
        gll16(Abase + (size_t)m*512, &Ab[buf][(w<<5)+(j<<4)][0]);
        const int t = tb + r - shift;
        const unsigned short* srcB = (t >= 0) ? (h_in + (size_t)t*512 + kc + schunk)
                                              : (zerobuf + schunk);
        gll16(srcB, &Bb[buf][(w<<5)+(j<<4)][0]);
      }
    };

    stage(0, 0);
    for (int s=0; s<48; ++s) {
      const int cur = s & 1;
      __syncthreads();
      if (s+1 < 48) stage(cur^1, s+1);
      f16x8 af[2], ag[2], bf[4];
      #pragma unroll
      for (int mf=0;mf<2;++mf){
        const int row = (wr<<5) + (mf<<4) + lr;
        af[mf] = ldh(&Ab[cur][row][lc<<3]);
        ag[mf] = ldh(&Ab[cur][64+row][lc<<3]);
      }
      #pragma unroll
      for (int nf=0;nf<4;++nf)
        bf[nf] = ldh(&Bb[cur][(wc<<6)+(nf<<4)+lr][lc<<3]);
      #pragma unroll
      for (int mf=0;mf<2;++mf)
        #pragma unroll
        for (int nf=0;nf<4;++nf){
          fa[mf][nf] = MFMA16(af[mf], bf[nf], fa[mf][nf]);
          ga[mf][nf] = MFMA16(ag[mf], bf[nf], ga[mf][nf]);
        }
    }

    // gating epilogue -> pre[t][m]
    #pragma unroll
    for (int mf=0;mf<2;++mf)
      #pragma unroll
      for (int nf=0;nf<4;++nf){
        const int m0 = mt*64 + (wr<<5) + (mf<<4) + (lc<<2);
        const int t  = tb + (wc<<6) + (nf<<4) + lr;
        float pv[4];
        #pragma unroll
        for (int r=0;r<4;++r){
          float f = fa[mf][nf][r] + cond[(size_t)(m0+r)*32 + e];
          float g = ga[mf][nf][r] + cond[(size_t)(m0+r+512)*32 + e];
          pv[r] = sigmoidf_(f) * tanhf_(g);
        }
        unsigned int* pp = (unsigned int*)&pre[(size_t)t*512 + m0];
        pp[0] = pack2(pv[0], pv[1]);
        pp[1] = pack2(pv[2], pv[3]);
      }
    __syncthreads();
    if (tid == 0){ __threadfence(); flag_add(&pre_cnt[nt]); }
    return;
  }

  // ================= ressk role =================
  const int b2 = blockIdx.x - 1024;
  const int nt = b2 & 127, rk = b2 >> 7;
  const int tb = nt << 7;
  const bool isres = (rk < 4);
  const unsigned short* W = isres ? Wres : Wskip;
  const int mrow0 = (isres ? rk : (rk-4)) * 128;

  if (tid == 0) spin_ge(&pre_cnt[nt], 8);
  __syncthreads();

  f32x4 acc[4][4];
  #pragma unroll
  for (int mf=0;mf<4;++mf)
    #pragma unroll
    for (int nf=0;nf<4;++nf) acc[mf][nf] = {0.f,0.f,0.f,0.f};

  auto stage2 = [&](int buf, int s){
    const int kc = s << 5;
    #pragma unroll
    for (int j=0;j<2;++j){
      const int r = srowA0 + (j<<4);
      gll16(W + (size_t)(mrow0 + r)*512 + kc + schunk, &Ab[buf][(w<<5)+(j<<4)][0]);
      gll16(pre + (size_t)(tb + r)*512 + kc + schunk, &Bb[buf][(w<<5)+(j<<4)][0]);
    }
  };

  stage2(0, 0);
  for (int s=0; s<16; ++s) {
    const int cur = s & 1;
    __syncthreads();
    if (s+1 < 16) stage2(cur^1, s+1);
    f16x8 a[4], bf[4];
    #pragma unroll
    for (int mf=0;mf<4;++mf)
      a[mf] = ldh(&Ab[cur][(wr<<6)+(mf<<4)+lr][lc<<3]);
    #pragma unroll
    for (int nf=0;nf<4;++nf)
      bf[nf] = ldh(&Bb[cur][(wc<<6)+(nf<<4)+lr][lc<<3]);
    #pragma unroll
    for (int mf=0;mf<4;++mf)
      #pragma unroll
      for (int nf=0;nf<4;++nf)
        acc[mf][nf] = MFMA16(a[mf], bf[nf], acc[mf][nf]);
  }

  if (isres) {
    #pragma unroll
    for (int mf=0;mf<4;++mf)
      #pragma unroll
      for (int nf=0;nf<4;++nf){
        const int m0 = mrow0 + (wr<<6) + (mf<<4) + (lc<<2);
        const int t  = tb + (wc<<6) + (nf<<4) + lr;
        const unsigned int* hi = (const unsigned int*)&h_in[(size_t)t*512 + m0];
        unsigned int h01 = hi[0], h23 = hi[1];
        float v0 = uplo(h01) + acc[mf][nf][0] + b_res[m0+0];
        float v1 = uphi(h01) + acc[mf][nf][1] + b_res[m0+1];
        float v2 = uplo(h23) + acc[mf][nf][2] + b_res[m0+2];
        float v3 = uphi(h23) + acc[mf][nf][3] + b_res[m0+3];
        unsigned int* hb = (unsigned int*)&h_out[(size_t)t*512 + m0];
        hb[0] = pack2(v0,v1); hb[1] = pack2(v2,v3);
      }
  } else {
    #pragma unroll
    for (int mf=0;mf<4;++mf)
      #pragma unroll
      for (int nf=0;nf<4;++nf){
        const int s0 = mrow0 + (wr<<6) + (mf<<4) + (lc<<2);
        const int t  = tb + (wc<<6) + (nf<<4) + lr;
        unsigned int* sp = (unsigned int*)&skip16[(size_t)t*256 + s0];
        unsigned int s01 = sp[0], s23 = sp[1];
        float v0 = uplo(s01) + acc[mf][nf][0] + b_skip[s0+0];
        float v1 = uphi(s01) + acc[mf][nf][1] + b_skip[s0+1];
        float v2 = uplo(s23) + acc[mf][nf][2] + b_skip[s0+2];
        float v3 = uphi(s23) + acc[mf][nf][3] + b_skip[s0+3];
        sp[0] = pack2(v0,v1); sp[1] = pack2(v2,v3);
      }
  }
}

// ---------------- final head ----------------
__global__ __launch_bounds__(512) void final_kernel(
    const unsigned short* __restrict__ skip16, const unsigned short* __restrict__ Wfs,
    const float* __restrict__ b_fskip, const float* __restrict__ fcond,
    const unsigned short* __restrict__ Wq, const float* __restrict__ b_quant,
    float* __restrict__ out) {
  __shared__ unsigned short S1[64][264];
  __shared__ unsigned short S2[64][264];
  int tid=threadIdx.x, w=tid>>6, l=tid&63, lr=l&15, lc=l>>4;
  int tb = blockIdx.x<<6, e = tb>>9;

  for (int j = tid; j < 64*32; j += 512) {
    int r  = j >> 5;
    int c8 = (j & 31) << 3;
    const unsigned int* sp = (const unsigned int*)&skip16[(size_t)(tb+r)*256 + c8];
    unsigned int* dp = (unsigned int*)&S1[r][c8];
    #pragma unroll
    for (int q=0;q<4;++q){
      unsigned int u = sp[q];
      dp[q] = pack2(fmaxf(uplo(u),0.f), fmaxf(uphi(u),0.f));
    }
  }
  __syncthreads();

  f32x4 acc[2][4];
  #pragma unroll
  for (int mf=0;mf<2;++mf)
    #pragma unroll
    for (int nf=0;nf<4;++nf) acc[mf][nf] = {0.f,0.f,0.f,0.f};
  for (int kc=0;kc<256;kc+=32) {
    f16x8 b[4];
    #pragma unroll
    for (int nf=0;nf<4;++nf) b[nf] = ldh(&S1[16*nf+lr][kc + lc*8]);
    #pragma unroll
    for (int mf=0;mf<2;++mf) {
      f16x8 a = ldh(&Wfs[(size_t)(w*32+16*mf+lr)*256 + kc + lc*8]);
      #pragma unroll
      for (int nf=0;nf<4;++nf)
        acc[mf][nf] = MFMA16(a, b[nf], acc[mf][nf]);
    }
  }
  #pragma unroll
  for (int mf=0;mf<2;++mf)
    #pragma unroll
    for (int nf=0;nf<4;++nf) {
      int m0 = w*32+16*mf+4*lc;
      int n  = 16*nf+lr;
      float pv[4];
      #pragma unroll
      for (int r=0;r<4;++r) {
        float v = acc[mf][nf][r] + b_fskip[m0+r] + fcond[(size_t)(m0+r)*32 + e];
        pv[r] = fmaxf(v, 0.f);
      }
      unsigned int* pp = (unsigned int*)&S2[n][m0];
      pp[0] = pack2(pv[0],pv[1]); pp[1] = pack2(pv[2],pv[3]);
    }
  __syncthreads();

  f32x4 acc2[2][4];
  #pragma unroll
  for (int mf=0;mf<2;++mf)
    #pragma unroll
    for (int nf=0;nf<4;++nf) acc2[mf][nf] = {0.f,0.f,0.f,0.f};
  for (int kc=0;kc<256;kc+=32) {
    f16x8 b[4];
    #pragma unroll
    for (int nf=0;nf<4;++nf) b[nf] = ldh(&S2[16*nf+lr][kc + lc*8]);
    #pragma unroll
    for (int mf=0;mf<2;++mf) {
      f16x8 a = ldh(&Wq[(size_t)(w*32+16*mf+lr)*256 + kc + lc*8]);
      #pragma unroll
      for (int nf=0;nf<4;++nf)
        acc2[mf][nf] = MFMA16(a, b[nf], acc2[mf][nf]);
    }
  }
  #pragma unroll
  for (int mf=0;mf<2;++mf)
    #pragma unroll
    for (int nf=0;nf<4;++nf) {
      int q0 = w*32+16*mf+4*lc;
      int t  = tb + 16*nf + lr;
      #pragma unroll
      for (int r=0;r<4;++r)
        out[(size_t)(q0+r)*TLEN + t] = acc2[mf][nf][r] + b_quant[q0+r];
    }
}

// ---------------- host ----------------

extern "C" void kernel_launch(void* const* d_in, const int* in_sizes, int n_in,
                              void* d_out, int out_size, void* d_ws, size_t ws_size,
                              hipStream_t stream) {
  const float* x       = (const float*)d_in[0];
  const float* emb     = (const float*)d_in[1];
  const float* w_init  = (const float*)d_in[2];
  const float* b_init  = (const float*)d_in[3];
  const float* w_iskip = (const float*)d_in[4];
  const float* b_iskip = (const float*)d_in[5];
  const float* w_dil   = (const float*)d_in[6];
  const float* b_dil   = (const float*)d_in[7];
  const float* w_cond  = (const float*)d_in[8];
  const float* b_cond  = (const float*)d_in[9];
  const float* w_res   = (const float*)d_in[10];
  const float* b_res   = (const float*)d_in[11];
  const float* w_skip  = (const float*)d_in[12];
  const float* b_skip  = (const float*)d_in[13];
  const float* w_fskip = (const float*)d_in[14];
  const float* b_fskip = (const float*)d_in[15];
  const float* w_fcond = (const float*)d_in[16];
  const float* b_fcond = (const float*)d_in[17];
  const float* w_quant = (const float*)d_in[18];
  const float* b_quant = (const float*)d_in[19];
  float* out = (float*)d_out;

  char* ws = (char*)d_ws;
  size_t off = 0;
  auto carve = [&](size_t bytes) -> void* {
    void* p = ws + off;
    off += (bytes + 255) & ~(size_t)255;
    return p;
  };
  unsigned short* A_dil     = (unsigned short*)carve((size_t)NSTACK*3*1024*512*2);
  unsigned short* Wres_h    = (unsigned short*)carve((size_t)NSTACK*512*512*2);
  unsigned short* Wskip_h   = (unsigned short*)carve((size_t)NSTACK*256*512*2);
  unsigned short* Wiskip_h  = (unsigned short*)carve((size_t)256*512*2);
  unsigned short* Wfskip_h  = (unsigned short*)carve((size_t)256*256*2);
  unsigned short* Wquant_h  = (unsigned short*)carve((size_t)256*256*2);
  unsigned short* h_h16     = (unsigned short*)carve((size_t)2*TLEN*512*2);
  unsigned short* pre_h16   = (unsigned short*)carve((size_t)TLEN*512*2);
  unsigned short* skip_h16  = (unsigned short*)carve((size_t)TLEN*256*2);
  float*          cond_all  = (float*)carve((size_t)NSTACK*1024*32*4);
  float*          fcond_all = (float*)carve((size_t)256*32*4);
  unsigned short* zerobuf   = (unsigned short*)carve((size_t)512*2);
  int*            flags     = (int*)carve((size_t)NSTACK*128*4);
  if (off > ws_size) return;

  hipMemsetAsync(zerobuf, 0, 512*2, stream);
  hipMemsetAsync(flags, 0, (size_t)NSTACK*128*4, stream);

  cast_f16_kernel<<<(NSTACK*512*512/4 + 255)/256, 256, 0, stream>>>(w_res,   Wres_h,   NSTACK*512*512/4);
  cast_f16_kernel<<<(NSTACK*256*512/4 + 255)/256, 256, 0, stream>>>(w_skip,  Wskip_h,  NSTACK*256*512/4);
  cast_f16_kernel<<<(256*512/4 + 255)/256,        256, 0, stream>>>(w_iskip, Wiskip_h, 256*512/4);
  cast_f16_kernel<<<(256*256/4 + 255)/256,        256, 0, stream>>>(w_fskip, Wfskip_h, 256*256/4);
  cast_f16_kernel<<<(256*256/4 + 255)/256,        256, 0, stream>>>(w_quant, Wquant_h, 256*256/4);
  transpose_wdil_kernel<<<(NSTACK*1024*512 + 255)/256, 256, 0, stream>>>(w_dil, A_dil);
  cond_kernel<<<(NSTACK*1024 + 256 + 255)/256, 256, 0, stream>>>(
      emb, w_cond, b_cond, b_dil, w_fcond, b_fcond, cond_all, fcond_all);

  h0_kernel<<<TLEN*128/256, 256, 0, stream>>>(x, w_init, b_init, h_h16);
  skip_init_kernel<<<TLEN/64, 512, 0, stream>>>(h_h16, Wiskip_h, b_iskip, skip_h16);

  const size_t HB = (size_t)TLEN*512;
  for (int i = 0; i < NSTACK; ++i) {
    int d = 1 << (i % 10);
    const unsigned short* h_in = h_h16 + (size_t)(i & 1)*HB;
    unsigned short* h_out      = h_h16 + (size_t)((i + 1) & 1)*HB;
    layer_kernel<<<1792, 256, 0, stream>>>(
        h_in,
        h_out,
        pre_h16,
        skip_h16,
        A_dil + (size_t)i*3*1024*512,
        Wres_h + (size_t)i*512*512,
        Wskip_h + (size_t)i*256*512,
        cond_all + (size_t)i*1024*32,
        b_res + (size_t)i*512,
        b_skip + (size_t)i*256,
        zerobuf,
        d,
        flags + (size_t)i*128);
  }

  final_kernel<<<TLEN/64, 512, 0, stream>>>(
      skip_h16, Wfskip_h, b_fskip, fcond_all, Wquant_h, b_quant, out);
}

// Round 15
// 3011.426 us; speedup vs baseline: 2.1172x; 2.1172x over previous
//
#include <hip/hip_runtime.h>

// WaveNet decoder for MI355X (gfx950) — round-13 base (best 3.11ms, separate
// launches, fp16 state), dil widened to BN=256 (512 thr / 8 waves, 2Mx4N):
// A-tile amortized over 2x N -> A staging halves, 3 gll per wave-K-step vs 4,
// same 16 MFMA + 8 ds_read per wave-step, LDS 48KB, 2 blocks/CU.
// Grid 512 = nt(0..63)|mt(0..7); same-nt blocks 64 apart -> same XCD L2.

typedef _Float16 f16x8 __attribute__((ext_vector_type(8)));
typedef float f32x4 __attribute__((ext_vector_type(4)));

#define NSTACK 30
#define TLEN   16384

typedef __attribute__((address_space(1))) const unsigned int glob_u32;
typedef __attribute__((address_space(3))) unsigned int lds_u32;

__device__ __forceinline__ void gll16(const unsigned short* g, unsigned short* l) {
  __builtin_amdgcn_global_load_lds((glob_u32*)g, (lds_u32*)l, 16, 0, 0);
}

__device__ __forceinline__ unsigned short f2h(float x) {
  union { _Float16 h; unsigned short u; } c;
  c.h = (_Float16)x;
  return c.u;
}
__device__ __forceinline__ unsigned pack2(float a, float b) {
  return (unsigned)f2h(a) | ((unsigned)f2h(b) << 16);
}
__device__ __forceinline__ float uplo(unsigned u){ union{unsigned v;_Float16 h[2];}c; c.v=u; return (float)c.h[0]; }
__device__ __forceinline__ float uphi(unsigned u){ union{unsigned v;_Float16 h[2];}c; c.v=u; return (float)c.h[1]; }
__device__ __forceinline__ f16x8 ldh(const unsigned short* p) {
  return *(const f16x8*)p;
}
__device__ __forceinline__ float sigmoidf_(float x){ return 1.0f/(1.0f+__expf(-x)); }
__device__ __forceinline__ float tanhf_(float x){ return 1.0f - 2.0f/(__expf(2.0f*x)+1.0f); }
#define MFMA16(a,b,c) __builtin_amdgcn_mfma_f32_16x16x32_f16((a),(b),(c),0,0,0)

// ---------------- small prep kernels ----------------

__global__ void cast_f16_kernel(const float* __restrict__ src,
                                unsigned short* __restrict__ dst, int n4) {
  int g = blockIdx.x*256 + threadIdx.x;
  if (g >= n4) return;
  f32x4 v = *(const f32x4*)(src + 4*(size_t)g);
  unsigned int* d = (unsigned int*)(dst + 4*(size_t)g);
  d[0] = pack2(v[0], v[1]);
  d[1] = pack2(v[2], v[3]);
}

// w_dil [30][1024][512][3] f32 -> A_dil [30][3][1024][512] fp16
__global__ void transpose_wdil_kernel(const float* __restrict__ src,
                                      unsigned short* __restrict__ dst) {
  int g = blockIdx.x*256 + threadIdx.x;
  if (g >= NSTACK*1024*512) return;
  int c = g & 511;
  int m = (g >> 9) & 1023;
  int i = g >> 19;
  const float* s = src + (size_t)g*3;
  #pragma unroll
  for (int tap=0; tap<3; ++tap)
    dst[(((size_t)i*3+tap)*1024 + m)*512 + c] = f2h(s[tap]);
}

// cond_all[i][m][e], fcond_all[m][e]
__global__ void cond_kernel(const float* __restrict__ emb,
                            const float* __restrict__ w_cond, const float* __restrict__ b_cond,
                            const float* __restrict__ b_dil,
                            const float* __restrict__ w_fcond, const float* __restrict__ b_fcond,
                            float* __restrict__ cond_all, float* __restrict__ fcond_all) {
  int g = blockIdx.x*256 + threadIdx.x;
  if (g < NSTACK*1024) {
    float acc[32];
    float base = b_cond[g] + b_dil[g];
    #pragma unroll
    for (int e=0;e<32;++e) acc[e] = base;
    #pragma unroll
    for (int c=0;c<16;++c) {
      float wv = w_cond[(size_t)g*16 + c];
      #pragma unroll
      for (int e=0;e<32;++e) acc[e] += wv * emb[c*32+e];
    }
    #pragma unroll
    for (int e=0;e<32;++e) cond_all[(size_t)g*32+e] = acc[e];
  } else if (g < NSTACK*1024 + 256) {
    int m = g - NSTACK*1024;
    float acc[32];
    float base = b_fcond[m];
    #pragma unroll
    for (int e=0;e<32;++e) acc[e] = base;
    #pragma unroll
    for (int c=0;c<16;++c) {
      float wv = w_fcond[(size_t)m*16 + c];
      #pragma unroll
      for (int e=0;e<32;++e) acc[e] += wv * emb[c*32+e];
    }
    #pragma unroll
    for (int e=0;e<32;++e) fcond_all[(size_t)m*32+e] = acc[e];
  }
}

// h0[t][c] = causal k3 conv of x + b_init -> fp16 ping.
__global__ void h0_kernel(const float* __restrict__ x, const float* __restrict__ w_init,
                          const float* __restrict__ b_init,
                          unsigned short* __restrict__ h_h16) {
  int g = blockIdx.x*256 + threadIdx.x;
  int t = g >> 7;
  int c = (g & 127) << 2;
  float xm2 = (t>=2)? x[t-2] : 0.f;
  float xm1 = (t>=1)? x[t-1] : 0.f;
  float x0  = x[t];
  float hv[4];
  #pragma unroll
  for (int r=0;r<4;++r) {
    int cc = c + r;
    hv[r] = w_init[cc*3+0]*xm2 + w_init[cc*3+1]*xm1 + w_init[cc*3+2]*x0 + b_init[cc];
  }
  unsigned int* hb = (unsigned int*)&h_h16[(size_t)t*512 + c];
  hb[0] = pack2(hv[0],hv[1]); hb[1] = pack2(hv[2],hv[3]);
}

// skip16[t][s] = fp16(W_iskip @ h0 + b_iskip)
__global__ __launch_bounds__(512) void skip_init_kernel(
    const unsigned short* __restrict__ h_h16, const unsigned short* __restrict__ Wiskip,
    const float* __restrict__ b_iskip, unsigned short* __restrict__ skip16) {
  int tid=threadIdx.x, w=tid>>6, l=tid&63, lr=l&15, lc=l>>4;
  int tb = blockIdx.x<<6;
  f32x4 acc[2][4];
  #pragma unroll
  for (int mf=0;mf<2;++mf)
    #pragma unroll
    for (int nf=0;nf<4;++nf) acc[mf][nf] = {0.f,0.f,0.f,0.f};
  for (int kc=0;kc<512;kc+=32) {
    f16x8 b[4];
    #pragma unroll
    for (int nf=0;nf<4;++nf)
      b[nf] = ldh(&h_h16[(size_t)(tb+16*nf+lr)*512 + kc + lc*8]);
    #pragma unroll
    for (int mf=0;mf<2;++mf) {
      f16x8 a = ldh(&Wiskip[(size_t)(w*32+16*mf+lr)*512 + kc + lc*8]);
      #pragma unroll
      for (int nf=0;nf<4;++nf)
        acc[mf][nf] = MFMA16(a, b[nf], acc[mf][nf]);
    }
  }
  #pragma unroll
  for (int mf=0;mf<2;++mf)
    #pragma unroll
    for (int nf=0;nf<4;++nf) {
      int s0 = w*32+16*mf+4*lc;
      int t  = tb+16*nf+lr;
      unsigned int* pp = (unsigned int*)&skip16[(size_t)t*256+s0];
      pp[0] = pack2(acc[mf][nf][0]+b_iskip[s0+0], acc[mf][nf][1]+b_iskip[s0+1]);
      pp[1] = pack2(acc[mf][nf][2]+b_iskip[s0+2], acc[mf][nf][3]+b_iskip[s0+3]);
    }
}

// ---------------- K1: dilated conv + gating (m97 template, BN=256) ----------------
// grid = 512: nt = bid&63 (t-tile of 256), mt = bid>>6 (0..7).
// 512 threads / 8 waves: wr=w>>2 (M-half: 32 filter + 32 gate rows),
// wc=w&3 (N-quarter: 64 cols). A-tile 128 rows (64 filter mt*64.. + 64 gate
// +512); B-tile 256 t-rows. BK=32 double-buffered; per wave-step: 1 A gll +
// 2 B gll, 8 ds_read, 16 MFMA. LDS 48KB -> 2 blocks/CU resident.
__global__ __launch_bounds__(512, 2) void dil_kernel(
    const unsigned short* __restrict__ h_in,    // [T][512] fp16
    unsigned short* __restrict__ pre,           // [T][512] fp16
    const unsigned short* __restrict__ A_dil,   // [3][1024][512] fp16
    const float* __restrict__ cond,             // [1024][32]
    const unsigned short* __restrict__ zerobuf, // zeros
    int dilation) {
  __shared__ unsigned short Ab[2][128][32];
  __shared__ unsigned short Bb[2][256][32];
  const int tid = threadIdx.x;
  const int w = tid >> 6, l = tid & 63;
  const int lr = l & 15, lc = l >> 4;
  const int nt = blockIdx.x & 63, mt = blockIdx.x >> 6;
  const int tb = nt << 8;
  const int e  = tb >> 9;
  const int wr = w >> 2, wc = w & 3;

  const int srowA = (w<<4) + (l>>2);           // A: wave stages 16 rows (1 gll)
  const int srowB0 = (w<<5) + (l>>2);          // B: 2 gll, +j*16
  const int schunk = (l & 3) << 3;             // shorts

  f32x4 fa[2][4], ga[2][4];
  #pragma unroll
  for (int mf=0;mf<2;++mf)
    #pragma unroll
    for (int nf=0;nf<4;++nf) { fa[mf][nf] = {0.f,0.f,0.f,0.f}; ga[mf][nf] = {0.f,0.f,0.f,0.f}; }

  auto stage = [&](int buf, int s){
    const int tap = s >> 4;
    const int kc  = (s & 15) << 5;
    const int shift = (2 - tap) * dilation;
    // A: 16 rows
    {
      const int r = srowA;
      const int m = mt*64 + r + ((r>>6)*448);  // r<64: filter ; r>=64: gate+512
      gll16(A_dil + (size_t)tap*(1024*512) + (size_t)m*512 + kc + schunk,
            &Ab[buf][(w<<4)][0]);
    }
    // B: 32 rows
    #pragma unroll
    for (int j=0;j<2;++j){
      const int r = srowB0 + (j<<4);
      const int t = tb + r - shift;
      const unsigned short* srcB = (t >= 0) ? (h_in + (size_t)t*512 + kc + schunk)
                                            : (zerobuf + schunk);
      gll16(srcB, &Bb[buf][(w<<5)+(j<<4)][0]);
    }
  };

  stage(0, 0);
  for (int s=0; s<48; ++s) {
    const int cur = s & 1;
    __syncthreads();                    // drains stage(s) + syncs reads of buf^1
    if (s+1 < 48) stage(cur^1, s+1);
    f16x8 af[2], ag[2], bf[4];
    #pragma unroll
    for (int mf=0;mf<2;++mf){
      const int row = (wr<<5) + (mf<<4) + lr;   // 0..63 filter rows
      af[mf] = ldh(&Ab[cur][row][lc<<3]);
      ag[mf] = ldh(&Ab[cur][64+row][lc<<3]);
    }
    #pragma unroll
    for (int nf=0;nf<4;++nf)
      bf[nf] = ldh(&Bb[cur][(wc<<6)+(nf<<4)+lr][lc<<3]);
    #pragma unroll
    for (int mf=0;mf<2;++mf)
      #pragma unroll
      for (int nf=0;nf<4;++nf){
        fa[mf][nf] = MFMA16(af[mf], bf[nf], fa[mf][nf]);
        ga[mf][nf] = MFMA16(ag[mf], bf[nf], ga[mf][nf]);
      }
  }

  // gating epilogue -> pre[t][m]
  #pragma unroll
  for (int mf=0;mf<2;++mf)
    #pragma unroll
    for (int nf=0;nf<4;++nf){
      const int m0 = mt*64 + (wr<<5) + (mf<<4) + (lc<<2);
      const int t  = tb + (wc<<6) + (nf<<4) + lr;
      float pv[4];
      #pragma unroll
      for (int r=0;r<4;++r){
        float f = fa[mf][nf][r] + cond[(size_t)(m0+r)*32 + e];
        float g = ga[mf][nf][r] + cond[(size_t)(m0+r+512)*32 + e];
        pv[r] = sigmoidf_(f) * tanhf_(g);
      }
      unsigned int* pp = (unsigned int*)&pre[(size_t)t*512 + m0];
      pp[0] = pack2(pv[0], pv[1]);
      pp[1] = pack2(pv[2], pv[3]);
    }
}

// ---------------- K2: res + skip GEMMs (128x128 m97 tiles, fp16 state) ----------------
// grid = 768: nt = bid&127, mt = bid>>7 in 0..5.
// mt<4: res rows [mt*128,+128): h_out = fp16(h_in + acc + b_res).
// mt>=4: skip rows [(mt-4)*128,+128): skip16 += acc + b_skip (fp16 RMW).
__global__ __launch_bounds__(256, 3) void ressk_kernel(
    const unsigned short* __restrict__ pre,     // [T][512] fp16
    const unsigned short* __restrict__ h_in,    // [T][512] fp16 ping
    unsigned short* __restrict__ h_out,         // [T][512] fp16 pong
    unsigned short* __restrict__ skip16,        // [T][256] fp16 (RMW)
    const unsigned short* __restrict__ Wres,    // [512][512] fp16
    const unsigned short* __restrict__ Wskip,   // [256][512] fp16
    const float* __restrict__ b_res,
    const float* __restrict__ b_skip) {
  __shared__ unsigned short Ab[2][128][32];
  __shared__ unsigned short Bb[2][128][32];
  const int tid = threadIdx.x;
  const int w = tid >> 6, l = tid & 63;
  const int lr = l & 15, lc = l >> 4;
  const int nt = blockIdx.x & 127, mt = blockIdx.x >> 7;
  const int tb = nt << 7;
  const int wr = w >> 1, wc = w & 1;
  const bool isres = (mt < 4);
  const unsigned short* W = isres ? Wres : Wskip;
  const int mrow0 = (isres ? mt : (mt-4)) * 128;

  const int srowA0 = (w<<5) + (l>>2);
  const int schunk = (l & 3) << 3;

  f32x4 acc[4][4];
  #pragma unroll
  for (int mf=0;mf<4;++mf)
    #pragma unroll
    for (int nf=0;nf<4;++nf) acc[mf][nf] = {0.f,0.f,0.f,0.f};

  auto stage = [&](int buf, int s){
    const int kc = s << 5;
    #pragma unroll
    for (int j=0;j<2;++j){
      const int r = srowA0 + (j<<4);
      gll16(W + (size_t)(mrow0 + r)*512 + kc + schunk, &Ab[buf][(w<<5)+(j<<4)][0]);
      gll16(pre + (size_t)(tb + r)*512 + kc + schunk, &Bb[buf][(w<<5)+(j<<4)][0]);
    }
  };

  stage(0, 0);
  for (int s=0; s<16; ++s) {
    const int cur = s & 1;
    __syncthreads();
    if (s+1 < 16) stage(cur^1, s+1);
    f16x8 a[4], bf[4];
    #pragma unroll
    for (int mf=0;mf<4;++mf)
      a[mf] = ldh(&Ab[cur][(wr<<6)+(mf<<4)+lr][lc<<3]);
    #pragma unroll
    for (int nf=0;nf<4;++nf)
      bf[nf] = ldh(&Bb[cur][(wc<<6)+(nf<<4)+lr][lc<<3]);
    #pragma unroll
    for (int mf=0;mf<4;++mf)
      #pragma unroll
      for (int nf=0;nf<4;++nf)
        acc[mf][nf] = MFMA16(a[mf], bf[nf], acc[mf][nf]);
  }

  if (isres) {
    #pragma unroll
    for (int mf=0;mf<4;++mf)
      #pragma unroll
      for (int nf=0;nf<4;++nf){
        const int m0 = mrow0 + (wr<<6) + (mf<<4) + (lc<<2);
        const int t  = tb + (wc<<6) + (nf<<4) + lr;
        const unsigned int* hi = (const unsigned int*)&h_in[(size_t)t*512 + m0];
        unsigned int h01 = hi[0], h23 = hi[1];
        float v0 = uplo(h01) + acc[mf][nf][0] + b_res[m0+0];
        float v1 = uphi(h01) + acc[mf][nf][1] + b_res[m0+1];
        float v2 = uplo(h23) + acc[mf][nf][2] + b_res[m0+2];
        float v3 = uphi(h23) + acc[mf][nf][3] + b_res[m0+3];
        unsigned int* hb = (unsigned int*)&h_out[(size_t)t*512 + m0];
        hb[0] = pack2(v0,v1); hb[1] = pack2(v2,v3);
      }
  } else {
    #pragma unroll
    for (int mf=0;mf<4;++mf)
      #pragma unroll
      for (int nf=0;nf<4;++nf){
        const int s0 = mrow0 + (wr<<6) + (mf<<4) + (lc<<2);
        const int t  = tb + (wc<<6) + (nf<<4) + lr;
        unsigned int* sp = (unsigned int*)&skip16[(size_t)t*256 + s0];
        unsigned int s01 = sp[0], s23 = sp[1];
        float v0 = uplo(s01) + acc[mf][nf][0] + b_skip[s0+0];
        float v1 = uphi(s01) + acc[mf][nf][1] + b_skip[s0+1];
        float v2 = uplo(s23) + acc[mf][nf][2] + b_skip[s0+2];
        float v3 = uphi(s23) + acc[mf][nf][3] + b_skip[s0+3];
        sp[0] = pack2(v0,v1); sp[1] = pack2(v2,v3);
      }
  }
}

// ---------------- final head ----------------
__global__ __launch_bounds__(512) void final_kernel(
    const unsigned short* __restrict__ skip16, const unsigned short* __restrict__ Wfs,
    const float* __restrict__ b_fskip, const float* __restrict__ fcond,
    const unsigned short* __restrict__ Wq, const float* __restrict__ b_quant,
    float* __restrict__ out) {
  __shared__ unsigned short S1[64][264];
  __shared__ unsigned short S2[64][264];
  int tid=threadIdx.x, w=tid>>6, l=tid&63, lr=l&15, lc=l>>4;
  int tb = blockIdx.x<<6, e = tb>>9;

  for (int j = tid; j < 64*32; j += 512) {
    int r  = j >> 5;
    int c8 = (j & 31) << 3;
    const unsigned int* sp = (const unsigned int*)&skip16[(size_t)(tb+r)*256 + c8];
    unsigned int* dp = (unsigned int*)&S1[r][c8];
    #pragma unroll
    for (int q=0;q<4;++q){
      unsigned int u = sp[q];
      dp[q] = pack2(fmaxf(uplo(u),0.f), fmaxf(uphi(u),0.f));
    }
  }
  __syncthreads();

  f32x4 acc[2][4];
  #pragma unroll
  for (int mf=0;mf<2;++mf)
    #pragma unroll
    for (int nf=0;nf<4;++nf) acc[mf][nf] = {0.f,0.f,0.f,0.f};
  for (int kc=0;kc<256;kc+=32) {
    f16x8 b[4];
    #pragma unroll
    for (int nf=0;nf<4;++nf) b[nf] = ldh(&S1[16*nf+lr][kc + lc*8]);
    #pragma unroll
    for (int mf=0;mf<2;++mf) {
      f16x8 a = ldh(&Wfs[(size_t)(w*32+16*mf+lr)*256 + kc + lc*8]);
      #pragma unroll
      for (int nf=0;nf<4;++nf)
        acc[mf][nf] = MFMA16(a, b[nf], acc[mf][nf]);
    }
  }
  #pragma unroll
  for (int mf=0;mf<2;++mf)
    #pragma unroll
    for (int nf=0;nf<4;++nf) {
      int m0 = w*32+16*mf+4*lc;
      int n  = 16*nf+lr;
      float pv[4];
      #pragma unroll
      for (int r=0;r<4;++r) {
        float v = acc[mf][nf][r] + b_fskip[m0+r] + fcond[(size_t)(m0+r)*32 + e];
        pv[r] = fmaxf(v, 0.f);
      }
      unsigned int* pp = (unsigned int*)&S2[n][m0];
      pp[0] = pack2(pv[0],pv[1]); pp[1] = pack2(pv[2],pv[3]);
    }
  __syncthreads();

  f32x4 acc2[2][4];
  #pragma unroll
  for (int mf=0;mf<2;++mf)
    #pragma unroll
    for (int nf=0;nf<4;++nf) acc2[mf][nf] = {0.f,0.f,0.f,0.f};
  for (int kc=0;kc<256;kc+=32) {
    f16x8 b[4];
    #pragma unroll
    for (int nf=0;nf<4;++nf) b[nf] = ldh(&S2[16*nf+lr][kc + lc*8]);
    #pragma unroll
    for (int mf=0;mf<2;++mf) {
      f16x8 a = ldh(&Wq[(size_t)(w*32+16*mf+lr)*256 + kc + lc*8]);
      #pragma unroll
      for (int nf=0;nf<4;++nf)
        acc2[mf][nf] = MFMA16(a, b[nf], acc2[mf][nf]);
    }
  }
  #pragma unroll
  for (int mf=0;mf<2;++mf)
    #pragma unroll
    for (int nf=0;nf<4;++nf) {
      int q0 = w*32+16*mf+4*lc;
      int t  = tb + 16*nf + lr;
      #pragma unroll
      for (int r=0;r<4;++r)
        out[(size_t)(q0+r)*TLEN + t] = acc2[mf][nf][r] + b_quant[q0+r];
    }
}

// ---------------- host ----------------

extern "C" void kernel_launch(void* const* d_in, const int* in_sizes, int n_in,
                              void* d_out, int out_size, void* d_ws, size_t ws_size,
                              hipStream_t stream) {
  const float* x       = (const float*)d_in[0];
  const float* emb     = (const float*)d_in[1];
  const float* w_init  = (const float*)d_in[2];
  const float* b_init  = (const float*)d_in[3];
  const float* w_iskip = (const float*)d_in[4];
  const float* b_iskip = (const float*)d_in[5];
  const float* w_dil   = (const float*)d_in[6];
  const float* b_dil   = (const float*)d_in[7];
  const float* w_cond  = (const float*)d_in[8];
  const float* b_cond  = (const float*)d_in[9];
  const float* w_res   = (const float*)d_in[10];
  const float* b_res   = (const float*)d_in[11];
  const float* w_skip  = (const float*)d_in[12];
  const float* b_skip  = (const float*)d_in[13];
  const float* w_fskip = (const float*)d_in[14];
  const float* b_fskip = (const float*)d_in[15];
  const float* w_fcond = (const float*)d_in[16];
  const float* b_fcond = (const float*)d_in[17];
  const float* w_quant = (const float*)d_in[18];
  const float* b_quant = (const float*)d_in[19];
  float* out = (float*)d_out;

  char* ws = (char*)d_ws;
  size_t off = 0;
  auto carve = [&](size_t bytes) -> void* {
    void* p = ws + off;
    off += (bytes + 255) & ~(size_t)255;
    return p;
  };
  unsigned short* A_dil     = (unsigned short*)carve((size_t)NSTACK*3*1024*512*2);
  unsigned short* Wres_h    = (unsigned short*)carve((size_t)NSTACK*512*512*2);
  unsigned short* Wskip_h   = (unsigned short*)carve((size_t)NSTACK*256*512*2);
  unsigned short* Wiskip_h  = (unsigned short*)carve((size_t)256*512*2);
  unsigned short* Wfskip_h  = (unsigned short*)carve((size_t)256*256*2);
  unsigned short* Wquant_h  = (unsigned short*)carve((size_t)256*256*2);
  unsigned short* h_h16     = (unsigned short*)carve((size_t)2*TLEN*512*2);
  unsigned short* pre_h16   = (unsigned short*)carve((size_t)TLEN*512*2);
  unsigned short* skip_h16  = (unsigned short*)carve((size_t)TLEN*256*2);
  float*          cond_all  = (float*)carve((size_t)NSTACK*1024*32*4);
  float*          fcond_all = (float*)carve((size_t)256*32*4);
  unsigned short* zerobuf   = (unsigned short*)carve((size_t)512*2);
  if (off > ws_size) return;

  hipMemsetAsync(zerobuf, 0, 512*2, stream);

  cast_f16_kernel<<<(NSTACK*512*512/4 + 255)/256, 256, 0, stream>>>(w_res,   Wres_h,   NSTACK*512*512/4);
  cast_f16_kernel<<<(NSTACK*256*512/4 + 255)/256, 256, 0, stream>>>(w_skip,  Wskip_h,  NSTACK*256*512/4);
  cast_f16_kernel<<<(256*512/4 + 255)/256,        256, 0, stream>>>(w_iskip, Wiskip_h, 256*512/4);
  cast_f16_kernel<<<(256*256/4 + 255)/256,        256, 0, stream>>>(w_fskip, Wfskip_h, 256*256/4);
  cast_f16_kernel<<<(256*256/4 + 255)/256,        256, 0, stream>>>(w_quant, Wquant_h, 256*256/4);
  transpose_wdil_kernel<<<(NSTACK*1024*512 + 255)/256, 256, 0, stream>>>(w_dil, A_dil);
  cond_kernel<<<(NSTACK*1024 + 256 + 255)/256, 256, 0, stream>>>(
      emb, w_cond, b_cond, b_dil, w_fcond, b_fcond, cond_all, fcond_all);

  h0_kernel<<<TLEN*128/256, 256, 0, stream>>>(x, w_init, b_init, h_h16);
  skip_init_kernel<<<TLEN/64, 512, 0, stream>>>(h_h16, Wiskip_h, b_iskip, skip_h16);

  const size_t HB = (size_t)TLEN*512;
  for (int i = 0; i < NSTACK; ++i) {
    int d = 1 << (i % 10);
    const unsigned short* h_in = h_h16 + (size_t)(i & 1)*HB;
    unsigned short* h_out      = h_h16 + (size_t)((i + 1) & 1)*HB;
    dil_kernel<<<512, 512, 0, stream>>>(
        h_in,
        pre_h16,
        A_dil + (size_t)i*3*1024*512,
        cond_all + (size_t)i*1024*32,
        zerobuf,
        d);
    ressk_kernel<<<768, 256, 0, stream>>>(
        pre_h16,
        h_in,
        h_out,
        skip_h16,
        Wres_h + (size_t)i*512*512,
        Wskip_h + (size_t)i*256*512,
        b_res + (size_t)i*512,
        b_skip + (size_t)i*256);
  }

  final_kernel<<<TLEN/64, 512, 0, stream>>>(
      skip_h16, Wfskip_h, b_fskip, fcond_all, Wquant_h, b_quant, out);
}

// Round 16
// 3007.389 us; speedup vs baseline: 2.1200x; 1.0013x over previous
//
#include <hip/hip_runtime.h>

// WaveNet decoder for MI355X (gfx950) — round-15 base (best 3.01ms):
//   + ressk widened to BN=256 (512 thr / 8 waves, grid 384), 1A+2B gll per
//     16-MFMA wave-step (matches dil's winning ratio), smaller launch tail.
//   + dil launch_bounds (512,2)->(512,4): forces VGPR<=128 so 2 blocks/CU
//     (16 waves/CU) are guaranteed co-resident.
//   All inter-layer state fp16; 2-phase m97-style staging loops throughout.

typedef _Float16 f16x8 __attribute__((ext_vector_type(8)));
typedef float f32x4 __attribute__((ext_vector_type(4)));

#define NSTACK 30
#define TLEN   16384

typedef __attribute__((address_space(1))) const unsigned int glob_u32;
typedef __attribute__((address_space(3))) unsigned int lds_u32;

__device__ __forceinline__ void gll16(const unsigned short* g, unsigned short* l) {
  __builtin_amdgcn_global_load_lds((glob_u32*)g, (lds_u32*)l, 16, 0, 0);
}

__device__ __forceinline__ unsigned short f2h(float x) {
  union { _Float16 h; unsigned short u; } c;
  c.h = (_Float16)x;
  return c.u;
}
__device__ __forceinline__ unsigned pack2(float a, float b) {
  return (unsigned)f2h(a) | ((unsigned)f2h(b) << 16);
}
__device__ __forceinline__ float uplo(unsigned u){ union{unsigned v;_Float16 h[2];}c; c.v=u; return (float)c.h[0]; }
__device__ __forceinline__ float uphi(unsigned u){ union{unsigned v;_Float16 h[2];}c; c.v=u; return (float)c.h[1]; }
__device__ __forceinline__ f16x8 ldh(const unsigned short* p) {
  return *(const f16x8*)p;
}
__device__ __forceinline__ float sigmoidf_(float x){ return 1.0f/(1.0f+__expf(-x)); }
__device__ __forceinline__ float tanhf_(float x){ return 1.0f - 2.0f/(__expf(2.0f*x)+1.0f); }
#define MFMA16(a,b,c) __builtin_amdgcn_mfma_f32_16x16x32_f16((a),(b),(c),0,0,0)

// ---------------- small prep kernels ----------------

__global__ void cast_f16_kernel(const float* __restrict__ src,
                                unsigned short* __restrict__ dst, int n4) {
  int g = blockIdx.x*256 + threadIdx.x;
  if (g >= n4) return;
  f32x4 v = *(const f32x4*)(src + 4*(size_t)g);
  unsigned int* d = (unsigned int*)(dst + 4*(size_t)g);
  d[0] = pack2(v[0], v[1]);
  d[1] = pack2(v[2], v[3]);
}

// w_dil [30][1024][512][3] f32 -> A_dil [30][3][1024][512] fp16
__global__ void transpose_wdil_kernel(const float* __restrict__ src,
                                      unsigned short* __restrict__ dst) {
  int g = blockIdx.x*256 + threadIdx.x;
  if (g >= NSTACK*1024*512) return;
  int c = g & 511;
  int m = (g >> 9) & 1023;
  int i = g >> 19;
  const float* s = src + (size_t)g*3;
  #pragma unroll
  for (int tap=0; tap<3; ++tap)
    dst[(((size_t)i*3+tap)*1024 + m)*512 + c] = f2h(s[tap]);
}

// cond_all[i][m][e], fcond_all[m][e]
__global__ void cond_kernel(const float* __restrict__ emb,
                            const float* __restrict__ w_cond, const float* __restrict__ b_cond,
                            const float* __restrict__ b_dil,
                            const float* __restrict__ w_fcond, const float* __restrict__ b_fcond,
                            float* __restrict__ cond_all, float* __restrict__ fcond_all) {
  int g = blockIdx.x*256 + threadIdx.x;
  if (g < NSTACK*1024) {
    float acc[32];
    float base = b_cond[g] + b_dil[g];
    #pragma unroll
    for (int e=0;e<32;++e) acc[e] = base;
    #pragma unroll
    for (int c=0;c<16;++c) {
      float wv = w_cond[(size_t)g*16 + c];
      #pragma unroll
      for (int e=0;e<32;++e) acc[e] += wv * emb[c*32+e];
    }
    #pragma unroll
    for (int e=0;e<32;++e) cond_all[(size_t)g*32+e] = acc[e];
  } else if (g < NSTACK*1024 + 256) {
    int m = g - NSTACK*1024;
    float acc[32];
    float base = b_fcond[m];
    #pragma unroll
    for (int e=0;e<32;++e) acc[e] = base;
    #pragma unroll
    for (int c=0;c<16;++c) {
      float wv = w_fcond[(size_t)m*16 + c];
      #pragma unroll
      for (int e=0;e<32;++e) acc[e] += wv * emb[c*32+e];
    }
    #pragma unroll
    for (int e=0;e<32;++e) fcond_all[(size_t)m*32+e] = acc[e];
  }
}

// h0[t][c] = causal k3 conv of x + b_init -> fp16 ping.
__global__ void h0_kernel(const float* __restrict__ x, const float* __restrict__ w_init,
                          const float* __restrict__ b_init,
                          unsigned short* __restrict__ h_h16) {
  int g = blockIdx.x*256 + threadIdx.x;
  int t = g >> 7;
  int c = (g & 127) << 2;
  float xm2 = (t>=2)? x[t-2] : 0.f;
  float xm1 = (t>=1)? x[t-1] : 0.f;
  float x0  = x[t];
  float hv[4];
  #pragma unroll
  for (int r=0;r<4;++r) {
    int cc = c + r;
    hv[r] = w_init[cc*3+0]*xm2 + w_init[cc*3+1]*xm1 + w_init[cc*3+2]*x0 + b_init[cc];
  }
  unsigned int* hb = (unsigned int*)&h_h16[(size_t)t*512 + c];
  hb[0] = pack2(hv[0],hv[1]); hb[1] = pack2(hv[2],hv[3]);
}

// skip16[t][s] = fp16(W_iskip @ h0 + b_iskip)
__global__ __launch_bounds__(512) void skip_init_kernel(
    const unsigned short* __restrict__ h_h16, const unsigned short* __restrict__ Wiskip,
    const float* __restrict__ b_iskip, unsigned short* __restrict__ skip16) {
  int tid=threadIdx.x, w=tid>>6, l=tid&63, lr=l&15, lc=l>>4;
  int tb = blockIdx.x<<6;
  f32x4 acc[2][4];
  #pragma unroll
  for (int mf=0;mf<2;++mf)
    #pragma unroll
    for (int nf=0;nf<4;++nf) acc[mf][nf] = {0.f,0.f,0.f,0.f};
  for (int kc=0;kc<512;kc+=32) {
    f16x8 b[4];
    #pragma unroll
    for (int nf=0;nf<4;++nf)
      b[nf] = ldh(&h_h16[(size_t)(tb+16*nf+lr)*512 + kc + lc*8]);
    #pragma unroll
    for (int mf=0;mf<2;++mf) {
      f16x8 a = ldh(&Wiskip[(size_t)(w*32+16*mf+lr)*512 + kc + lc*8]);
      #pragma unroll
      for (int nf=0;nf<4;++nf)
        acc[mf][nf] = MFMA16(a, b[nf], acc[mf][nf]);
    }
  }
  #pragma unroll
  for (int mf=0;mf<2;++mf)
    #pragma unroll
    for (int nf=0;nf<4;++nf) {
      int s0 = w*32+16*mf+4*lc;
      int t  = tb+16*nf+lr;
      unsigned int* pp = (unsigned int*)&skip16[(size_t)t*256+s0];
      pp[0] = pack2(acc[mf][nf][0]+b_iskip[s0+0], acc[mf][nf][1]+b_iskip[s0+1]);
      pp[1] = pack2(acc[mf][nf][2]+b_iskip[s0+2], acc[mf][nf][3]+b_iskip[s0+3]);
    }
}

// ---------------- K1: dilated conv + gating (m97 template, BN=256) ----------------
// grid = 512: nt = bid&63 (t-tile of 256), mt = bid>>6 (0..7).
// 512 threads / 8 waves: wr=w>>2 (M-half: 32 filter + 32 gate rows),
// wc=w&3 (N-quarter: 64 cols). Per wave-step: 1 A gll + 2 B gll, 8 ds_read,
// 16 MFMA. LDS 48KB; launch_bounds(512,4) -> VGPR<=128 -> 2 blocks/CU.
__global__ __launch_bounds__(512, 4) void dil_kernel(
    const unsigned short* __restrict__ h_in,    // [T][512] fp16
    unsigned short* __restrict__ pre,           // [T][512] fp16
    const unsigned short* __restrict__ A_dil,   // [3][1024][512] fp16
    const float* __restrict__ cond,             // [1024][32]
    const unsigned short* __restrict__ zerobuf, // zeros
    int dilation) {
  __shared__ unsigned short Ab[2][128][32];
  __shared__ unsigned short Bb[2][256][32];
  const int tid = threadIdx.x;
  const int w = tid >> 6, l = tid & 63;
  const int lr = l & 15, lc = l >> 4;
  const int nt = blockIdx.x & 63, mt = blockIdx.x >> 6;
  const int tb = nt << 8;
  const int e  = tb >> 9;
  const int wr = w >> 2, wc = w & 3;

  const int srowA = (w<<4) + (l>>2);           // A: wave stages 16 rows (1 gll)
  const int srowB0 = (w<<5) + (l>>2);          // B: 2 gll, +j*16
  const int schunk = (l & 3) << 3;             // shorts

  f32x4 fa[2][4], ga[2][4];
  #pragma unroll
  for (int mf=0;mf<2;++mf)
    #pragma unroll
    for (int nf=0;nf<4;++nf) { fa[mf][nf] = {0.f,0.f,0.f,0.f}; ga[mf][nf] = {0.f,0.f,0.f,0.f}; }

  auto stage = [&](int buf, int s){
    const int tap = s >> 4;
    const int kc  = (s & 15) << 5;
    const int shift = (2 - tap) * dilation;
    {
      const int r = srowA;
      const int m = mt*64 + r + ((r>>6)*448);  // r<64: filter ; r>=64: gate+512
      gll16(A_dil + (size_t)tap*(1024*512) + (size_t)m*512 + kc + schunk,
            &Ab[buf][(w<<4)][0]);
    }
    #pragma unroll
    for (int j=0;j<2;++j){
      const int r = srowB0 + (j<<4);
      const int t = tb + r - shift;
      const unsigned short* srcB = (t >= 0) ? (h_in + (size_t)t*512 + kc + schunk)
                                            : (zerobuf + schunk);
      gll16(srcB, &Bb[buf][(w<<5)+(j<<4)][0]);
    }
  };

  stage(0, 0);
  for (int s=0; s<48; ++s) {
    const int cur = s & 1;
    __syncthreads();
    if (s+1 < 48) stage(cur^1, s+1);
    f16x8 af[2], ag[2], bf[4];
    #pragma unroll
    for (int mf=0;mf<2;++mf){
      const int row = (wr<<5) + (mf<<4) + lr;
      af[mf] = ldh(&Ab[cur][row][lc<<3]);
      ag[mf] = ldh(&Ab[cur][64+row][lc<<3]);
    }
    #pragma unroll
    for (int nf=0;nf<4;++nf)
      bf[nf] = ldh(&Bb[cur][(wc<<6)+(nf<<4)+lr][lc<<3]);
    #pragma unroll
    for (int mf=0;mf<2;++mf)
      #pragma unroll
      for (int nf=0;nf<4;++nf){
        fa[mf][nf] = MFMA16(af[mf], bf[nf], fa[mf][nf]);
        ga[mf][nf] = MFMA16(ag[mf], bf[nf], ga[mf][nf]);
      }
  }

  // gating epilogue -> pre[t][m]
  #pragma unroll
  for (int mf=0;mf<2;++mf)
    #pragma unroll
    for (int nf=0;nf<4;++nf){
      const int m0 = mt*64 + (wr<<5) + (mf<<4) + (lc<<2);
      const int t  = tb + (wc<<6) + (nf<<4) + lr;
      float pv[4];
      #pragma unroll
      for (int r=0;r<4;++r){
        float f = fa[mf][nf][r] + cond[(size_t)(m0+r)*32 + e];
        float g = ga[mf][nf][r] + cond[(size_t)(m0+r+512)*32 + e];
        pv[r] = sigmoidf_(f) * tanhf_(g);
      }
      unsigned int* pp = (unsigned int*)&pre[(size_t)t*512 + m0];
      pp[0] = pack2(pv[0], pv[1]);
      pp[1] = pack2(pv[2], pv[3]);
    }
}

// ---------------- K2: res + skip GEMMs (BN=256, M=128 tiles, fp16 state) ----------------
// grid = 384: nt = bid&63 (t-tile of 256), mt = bid>>6 in 0..5.
// mt<4: res rows [mt*128,+128): h_out = fp16(h_in + acc + b_res).
// mt>=4: skip rows [(mt-4)*128,+128): skip16 += acc + b_skip (fp16 RMW).
// 512 thr / 8 waves (2Mx4N): wave = 64 rows x 64 cols, acc[4][4].
// Per wave-step: 1 A gll + 2 B gll, 8 ds_read, 16 MFMA. LDS 48KB.
__global__ __launch_bounds__(512, 4) void ressk_kernel(
    const unsigned short* __restrict__ pre,     // [T][512] fp16
    const unsigned short* __restrict__ h_in,    // [T][512] fp16 ping
    unsigned short* __restrict__ h_out,         // [T][512] fp16 pong
    unsigned short* __restrict__ skip16,        // [T][256] fp16 (RMW)
    const unsigned short* __restrict__ Wres,    // [512][512] fp16
    const unsigned short* __restrict__ Wskip,   // [256][512] fp16
    const float* __restrict__ b_res,
    const float* __restrict__ b_skip) {
  __shared__ unsigned short Ab[2][128][32];
  __shared__ unsigned short Bb[2][256][32];
  const int tid = threadIdx.x;
  const int w = tid >> 6, l = tid & 63;
  const int lr = l & 15, lc = l >> 4;
  const int nt = blockIdx.x & 63, mt = blockIdx.x >> 6;
  const int tb = nt << 8;
  const int wr = w >> 2, wc = w & 3;
  const bool isres = (mt < 4);
  const unsigned short* W = isres ? Wres : Wskip;
  const int mrow0 = (isres ? mt : (mt-4)) * 128;

  const int srowA = (w<<4) + (l>>2);
  const int srowB0 = (w<<5) + (l>>2);
  const int schunk = (l & 3) << 3;

  f32x4 acc[4][4];
  #pragma unroll
  for (int mf=0;mf<4;++mf)
    #pragma unroll
    for (int nf=0;nf<4;++nf) acc[mf][nf] = {0.f,0.f,0.f,0.f};

  auto stage = [&](int buf, int s){
    const int kc = s << 5;
    gll16(W + (size_t)(mrow0 + srowA)*512 + kc + schunk, &Ab[buf][(w<<4)][0]);
    #pragma unroll
    for (int j=0;j<2;++j){
      const int r = srowB0 + (j<<4);
      gll16(pre + (size_t)(tb + r)*512 + kc + schunk, &Bb[buf][(w<<5)+(j<<4)][0]);
    }
  };

  stage(0, 0);
  for (int s=0; s<16; ++s) {
    const int cur = s & 1;
    __syncthreads();
    if (s+1 < 16) stage(cur^1, s+1);
    f16x8 a[4], bf[4];
    #pragma unroll
    for (int mf=0;mf<4;++mf)
      a[mf] = ldh(&Ab[cur][(wr<<6)+(mf<<4)+lr][lc<<3]);
    #pragma unroll
    for (int nf=0;nf<4;++nf)
      bf[nf] = ldh(&Bb[cur][(wc<<6)+(nf<<4)+lr][lc<<3]);
    #pragma unroll
    for (int mf=0;mf<4;++mf)
      #pragma unroll
      for (int nf=0;nf<4;++nf)
        acc[mf][nf] = MFMA16(a[mf], bf[nf], acc[mf][nf]);
  }

  if (isres) {
    #pragma unroll
    for (int mf=0;mf<4;++mf)
      #pragma unroll
      for (int nf=0;nf<4;++nf){
        const int m0 = mrow0 + (wr<<6) + (mf<<4) + (lc<<2);
        const int t  = tb + (wc<<6) + (nf<<4) + lr;
        const unsigned int* hi = (const unsigned int*)&h_in[(size_t)t*512 + m0];
        unsigned int h01 = hi[0], h23 = hi[1];
        float v0 = uplo(h01) + acc[mf][nf][0] + b_res[m0+0];
        float v1 = uphi(h01) + acc[mf][nf][1] + b_res[m0+1];
        float v2 = uplo(h23) + acc[mf][nf][2] + b_res[m0+2];
        float v3 = uphi(h23) + acc[mf][nf][3] + b_res[m0+3];
        unsigned int* hb = (unsigned int*)&h_out[(size_t)t*512 + m0];
        hb[0] = pack2(v0,v1); hb[1] = pack2(v2,v3);
      }
  } else {
    #pragma unroll
    for (int mf=0;mf<4;++mf)
      #pragma unroll
      for (int nf=0;nf<4;++nf){
        const int s0 = mrow0 + (wr<<6) + (mf<<4) + (lc<<2);
        const int t  = tb + (wc<<6) + (nf<<4) + lr;
        unsigned int* sp = (unsigned int*)&skip16[(size_t)t*256 + s0];
        unsigned int s01 = sp[0], s23 = sp[1];
        float v0 = uplo(s01) + acc[mf][nf][0] + b_skip[s0+0];
        float v1 = uphi(s01) + acc[mf][nf][1] + b_skip[s0+1];
        float v2 = uplo(s23) + acc[mf][nf][2] + b_skip[s0+2];
        float v3 = uphi(s23) + acc[mf][nf][3] + b_skip[s0+3];
        sp[0] = pack2(v0,v1); sp[1] = pack2(v2,v3);
      }
  }
}

// ---------------- final head ----------------
__global__ __launch_bounds__(512) void final_kernel(
    const unsigned short* __restrict__ skip16, const unsigned short* __restrict__ Wfs,
    const float* __restrict__ b_fskip, const float* __restrict__ fcond,
    const unsigned short* __restrict__ Wq, const float* __restrict__ b_quant,
    float* __restrict__ out) {
  __shared__ unsigned short S1[64][264];
  __shared__ unsigned short S2[64][264];
  int tid=threadIdx.x, w=tid>>6, l=tid&63, lr=l&15, lc=l>>4;
  int tb = blockIdx.x<<6, e = tb>>9;

  for (int j = tid; j < 64*32; j += 512) {
    int r  = j >> 5;
    int c8 = (j & 31) << 3;
    const unsigned int* sp = (const unsigned int*)&skip16[(size_t)(tb+r)*256 + c8];
    unsigned int* dp = (unsigned int*)&S1[r][c8];
    #pragma unroll
    for (int q=0;q<4;++q){
      unsigned int u = sp[q];
      dp[q] = pack2(fmaxf(uplo(u),0.f), fmaxf(uphi(u),0.f));
    }
  }
  __syncthreads();

  f32x4 acc[2][4];
  #pragma unroll
  for (int mf=0;mf<2;++mf)
    #pragma unroll
    for (int nf=0;nf<4;++nf) acc[mf][nf] = {0.f,0.f,0.f,0.f};
  for (int kc=0;kc<256;kc+=32) {
    f16x8 b[4];
    #pragma unroll
    for (int nf=0;nf<4;++nf) b[nf] = ldh(&S1[16*nf+lr][kc + lc*8]);
    #pragma unroll
    for (int mf=0;mf<2;++mf) {
      f16x8 a = ldh(&Wfs[(size_t)(w*32+16*mf+lr)*256 + kc + lc*8]);
      #pragma unroll
      for (int nf=0;nf<4;++nf)
        acc[mf][nf] = MFMA16(a, b[nf], acc[mf][nf]);
    }
  }
  #pragma unroll
  for (int mf=0;mf<2;++mf)
    #pragma unroll
    for (int nf=0;nf<4;++nf) {
      int m0 = w*32+16*mf+4*lc;
      int n  = 16*nf+lr;
      float pv[4];
      #pragma unroll
      for (int r=0;r<4;++r) {
        float v = acc[mf][nf][r] + b_fskip[m0+r] + fcond[(size_t)(m0+r)*32 + e];
        pv[r] = fmaxf(v, 0.f);
      }
      unsigned int* pp = (unsigned int*)&S2[n][m0];
      pp[0] = pack2(pv[0],pv[1]); pp[1] = pack2(pv[2],pv[3]);
    }
  __syncthreads();

  f32x4 acc2[2][4];
  #pragma unroll
  for (int mf=0;mf<2;++mf)
    #pragma unroll
    for (int nf=0;nf<4;++nf) acc2[mf][nf] = {0.f,0.f,0.f,0.f};
  for (int kc=0;kc<256;kc+=32) {
    f16x8 b[4];
    #pragma unroll
    for (int nf=0;nf<4;++nf) b[nf] = ldh(&S2[16*nf+lr][kc + lc*8]);
    #pragma unroll
    for (int mf=0;mf<2;++mf) {
      f16x8 a = ldh(&Wq[(size_t)(w*32+16*mf+lr)*256 + kc + lc*8]);
      #pragma unroll
      for (int nf=0;nf<4;++nf)
        acc2[mf][nf] = MFMA16(a, b[nf], acc2[mf][nf]);
    }
  }
  #pragma unroll
  for (int mf=0;mf<2;++mf)
    #pragma unroll
    for (int nf=0;nf<4;++nf) {
      int q0 = w*32+16*mf+4*lc;
      int t  = tb + 16*nf + lr;
      #pragma unroll
      for (int r=0;r<4;++r)
        out[(size_t)(q0+r)*TLEN + t] = acc2[mf][nf][r] + b_quant[q0+r];
    }
}

// ---------------- host ----------------

extern "C" void kernel_launch(void* const* d_in, const int* in_sizes, int n_in,
                              void* d_out, int out_size, void* d_ws, size_t ws_size,
                              hipStream_t stream) {
  const float* x       = (const float*)d_in[0];
  const float* emb     = (const float*)d_in[1];
  const float* w_init  = (const float*)d_in[2];
  const float* b_init  = (const float*)d_in[3];
  const float* w_iskip = (const float*)d_in[4];
  const float* b_iskip = (const float*)d_in[5];
  const float* w_dil   = (const float*)d_in[6];
  const float* b_dil   = (const float*)d_in[7];
  const float* w_cond  = (const float*)d_in[8];
  const float* b_cond  = (const float*)d_in[9];
  const float* w_res   = (const float*)d_in[10];
  const float* b_res   = (const float*)d_in[11];
  const float* w_skip  = (const float*)d_in[12];
  const float* b_skip  = (const float*)d_in[13];
  const float* w_fskip = (const float*)d_in[14];
  const float* b_fskip = (const float*)d_in[15];
  const float* w_fcond = (const float*)d_in[16];
  const float* b_fcond = (const float*)d_in[17];
  const float* w_quant = (const float*)d_in[18];
  const float* b_quant = (const float*)d_in[19];
  float* out = (float*)d_out;

  char* ws = (char*)d_ws;
  size_t off = 0;
  auto carve = [&](size_t bytes) -> void* {
    void* p = ws + off;
    off += (bytes + 255) & ~(size_t)255;
    return p;
  };
  unsigned short* A_dil     = (unsigned short*)carve((size_t)NSTACK*3*1024*512*2);
  unsigned short* Wres_h    = (unsigned short*)carve((size_t)NSTACK*512*512*2);
  unsigned short* Wskip_h   = (unsigned short*)carve((size_t)NSTACK*256*512*2);
  unsigned short* Wiskip_h  = (unsigned short*)carve((size_t)256*512*2);
  unsigned short* Wfskip_h  = (unsigned short*)carve((size_t)256*256*2);
  unsigned short* Wquant_h  = (unsigned short*)carve((size_t)256*256*2);
  unsigned short* h_h16     = (unsigned short*)carve((size_t)2*TLEN*512*2);
  unsigned short* pre_h16   = (unsigned short*)carve((size_t)TLEN*512*2);
  unsigned short* skip_h16  = (unsigned short*)carve((size_t)TLEN*256*2);
  float*          cond_all  = (float*)carve((size_t)NSTACK*1024*32*4);
  float*          fcond_all = (float*)carve((size_t)256*32*4);
  unsigned short* zerobuf   = (unsigned short*)carve((size_t)512*2);
  if (off > ws_size) return;

  hipMemsetAsync(zerobuf, 0, 512*2, stream);

  cast_f16_kernel<<<(NSTACK*512*512/4 + 255)/256, 256, 0, stream>>>(w_res,   Wres_h,   NSTACK*512*512/4);
  cast_f16_kernel<<<(NSTACK*256*512/4 + 255)/256, 256, 0, stream>>>(w_skip,  Wskip_h,  NSTACK*256*512/4);
  cast_f16_kernel<<<(256*512/4 + 255)/256,        256, 0, stream>>>(w_iskip, Wiskip_h, 256*512/4);
  cast_f16_kernel<<<(256*256/4 + 255)/256,        256, 0, stream>>>(w_fskip, Wfskip_h, 256*256/4);
  cast_f16_kernel<<<(256*256/4 + 255)/256,        256, 0, stream>>>(w_quant, Wquant_h, 256*256/4);
  transpose_wdil_kernel<<<(NSTACK*1024*512 + 255)/256, 256, 0, stream>>>(w_dil, A_dil);
  cond_kernel<<<(NSTACK*1024 + 256 + 255)/256, 256, 0, stream>>>(
      emb, w_cond, b_cond, b_dil, w_fcond, b_fcond, cond_all, fcond_all);

  h0_kernel<<<TLEN*128/256, 256, 0, stream>>>(x, w_init, b_init, h_h16);
  skip_init_kernel<<<TLEN/64, 512, 0, stream>>>(h_h16, Wiskip_h, b_iskip, skip_h16);

  const size_t HB = (size_t)TLEN*512;
  for (int i = 0; i < NSTACK; ++i) {
    int d = 1 << (i % 10);
    const unsigned short* h_in = h_h16 + (size_t)(i & 1)*HB;
    unsigned short* h_out      = h_h16 + (size_t)((i + 1) & 1)*HB;
    dil_kernel<<<512, 512, 0, stream>>>(
        h_in,
        pre_h16,
        A_dil + (size_t)i*3*1024*512,
        cond_all + (size_t)i*1024*32,
        zerobuf,
        d);
    ressk_kernel<<<384, 512, 0, stream>>>(
        pre_h16,
        h_in,
        h_out,
        skip_h16,
        Wres_h + (size_t)i*512*512,
        Wskip_h + (size_t)i*256*512,
        b_res + (size_t)i*512,
        b_skip + (size_t)i*256);
  }

  final_kernel<<<TLEN/64, 512, 0, stream>>>(
      skip_h16, Wfskip_h, b_fskip, fcond_all, Wquant_h, b_quant, out);
}

// Round 17
// 2914.761 us; speedup vs baseline: 2.1874x; 1.0318x over previous
//
#include <hip/hip_runtime.h>

// WaveNet decoder for MI355X (gfx950) — round-16 base (best 3.007ms) with
// launch-count reduction outside the GEMM bodies:
//   - ONE fused prep kernel (transpose_wdil + 5 casts + cond), flat-indexed.
//   - h0 + skip_init fused (h0 -> LDS + global; skip GEMM reads B from LDS).
//   - dil (BN=256, 8 waves) / ressk (BN=256) / final: unchanged.

typedef _Float16 f16x8 __attribute__((ext_vector_type(8)));
typedef float f32x4 __attribute__((ext_vector_type(4)));

#define NSTACK 30
#define TLEN   16384

typedef __attribute__((address_space(1))) const unsigned int glob_u32;
typedef __attribute__((address_space(3))) unsigned int lds_u32;

__device__ __forceinline__ void gll16(const unsigned short* g, unsigned short* l) {
  __builtin_amdgcn_global_load_lds((glob_u32*)g, (lds_u32*)l, 16, 0, 0);
}

__device__ __forceinline__ unsigned short f2h(float x) {
  union { _Float16 h; unsigned short u; } c;
  c.h = (_Float16)x;
  return c.u;
}
__device__ __forceinline__ unsigned pack2(float a, float b) {
  return (unsigned)f2h(a) | ((unsigned)f2h(b) << 16);
}
__device__ __forceinline__ float uplo(unsigned u){ union{unsigned v;_Float16 h[2];}c; c.v=u; return (float)c.h[0]; }
__device__ __forceinline__ float uphi(unsigned u){ union{unsigned v;_Float16 h[2];}c; c.v=u; return (float)c.h[1]; }
__device__ __forceinline__ f16x8 ldh(const unsigned short* p) {
  return *(const f16x8*)p;
}
__device__ __forceinline__ float sigmoidf_(float x){ return 1.0f/(1.0f+__expf(-x)); }
__device__ __forceinline__ float tanhf_(float x){ return 1.0f - 2.0f/(__expf(2.0f*x)+1.0f); }
#define MFMA16(a,b,c) __builtin_amdgcn_mfma_f32_16x16x32_f16((a),(b),(c),0,0,0)

// ---------------- fused prep kernel ----------------
// flat segments:
//  [0, 15728640)              transpose w_dil -> A_dil (per (i,m,c), 3 taps)
//  [+1966080)                 cast w_res   (f32x4 groups)
//  [+983040)                  cast w_skip
//  [+32768)                   cast w_iskip
//  [+16384)                   cast w_fskip
//  [+16384)                   cast w_quant
//  [+30976)                   cond (30*1024 rows + 256 fcond rows)
#define SEG_T  15728640L
#define SEG_R  1966080L
#define SEG_S  983040L
#define SEG_I  32768L
#define SEG_F  16384L
#define SEG_Q  16384L
#define SEG_C  30976L
#define PREP_TOTAL (SEG_T+SEG_R+SEG_S+SEG_I+SEG_F+SEG_Q+SEG_C)

__device__ __forceinline__ void cast4(const float* src, unsigned short* dst, long g){
  f32x4 v = *(const f32x4*)(src + 4*g);
  unsigned int* d = (unsigned int*)(dst + 4*g);
  d[0] = pack2(v[0], v[1]);
  d[1] = pack2(v[2], v[3]);
}

__global__ void prep_kernel(
    const float* __restrict__ w_dil,  unsigned short* __restrict__ A_dil,
    const float* __restrict__ w_res,  unsigned short* __restrict__ Wres_h,
    const float* __restrict__ w_skip, unsigned short* __restrict__ Wskip_h,
    const float* __restrict__ w_iskip,unsigned short* __restrict__ Wiskip_h,
    const float* __restrict__ w_fskip,unsigned short* __restrict__ Wfskip_h,
    const float* __restrict__ w_quant,unsigned short* __restrict__ Wquant_h,
    const float* __restrict__ emb,
    const float* __restrict__ w_cond, const float* __restrict__ b_cond,
    const float* __restrict__ b_dil,
    const float* __restrict__ w_fcond,const float* __restrict__ b_fcond,
    float* __restrict__ cond_all, float* __restrict__ fcond_all) {
  long g = (long)blockIdx.x*256 + threadIdx.x;
  if (g < SEG_T) {
    int c = (int)(g & 511);
    int m = (int)((g >> 9) & 1023);
    int i = (int)(g >> 19);
    const float* s = w_dil + g*3;
    #pragma unroll
    for (int tap=0; tap<3; ++tap)
      A_dil[(((size_t)i*3+tap)*1024 + m)*512 + c] = f2h(s[tap]);
    return;
  }
  g -= SEG_T;
  if (g < SEG_R) { cast4(w_res,  Wres_h,  g); return; }
  g -= SEG_R;
  if (g < SEG_S) { cast4(w_skip, Wskip_h, g); return; }
  g -= SEG_S;
  if (g < SEG_I) { cast4(w_iskip, Wiskip_h, g); return; }
  g -= SEG_I;
  if (g < SEG_F) { cast4(w_fskip, Wfskip_h, g); return; }
  g -= SEG_F;
  if (g < SEG_Q) { cast4(w_quant, Wquant_h, g); return; }
  g -= SEG_Q;
  if (g < NSTACK*1024) {
    int row = (int)g;
    float acc[32];
    float base = b_cond[row] + b_dil[row];
    #pragma unroll
    for (int e=0;e<32;++e) acc[e] = base;
    #pragma unroll
    for (int c=0;c<16;++c) {
      float wv = w_cond[(size_t)row*16 + c];
      #pragma unroll
      for (int e=0;e<32;++e) acc[e] += wv * emb[c*32+e];
    }
    #pragma unroll
    for (int e=0;e<32;++e) cond_all[(size_t)row*32+e] = acc[e];
  } else if (g < NSTACK*1024 + 256) {
    int m = (int)(g - NSTACK*1024);
    float acc[32];
    float base = b_fcond[m];
    #pragma unroll
    for (int c=0;c<16;++c) {
      float wv = w_fcond[(size_t)m*16 + c];
      #pragma unroll
      for (int e=0;e<32;++e) acc[e] = (c==0 ? base : acc[e]) + wv * emb[c*32+e];
    }
    #pragma unroll
    for (int e=0;e<32;++e) fcond_all[(size_t)m*32+e] = acc[e];
  }
}

// ---------------- fused h0 + skip_init ----------------
// grid 256, 512 threads. Block owns t rows [tb, tb+64).
// Phase 1: h0 (causal k3 conv + b_init) -> LDS S[64][520] (fp16) + global h16.
// Phase 2: skip16 = fp16(Wiskip @ h + b_iskip), B from LDS, A from global.
__global__ __launch_bounds__(512) void hs_kernel(
    const float* __restrict__ x, const float* __restrict__ w_init,
    const float* __restrict__ b_init,
    unsigned short* __restrict__ h_h16,
    const unsigned short* __restrict__ Wiskip,
    const float* __restrict__ b_iskip, unsigned short* __restrict__ skip16) {
  __shared__ unsigned short S[64][520];
  const int tid = threadIdx.x;
  const int tb = blockIdx.x << 6;

  for (int j = tid; j < 64*128; j += 512) {
    int r  = j >> 7;
    int c4 = (j & 127) << 2;
    int t  = tb + r;
    float xm2 = (t>=2)? x[t-2] : 0.f;
    float xm1 = (t>=1)? x[t-1] : 0.f;
    float x0  = x[t];
    float hv[4];
    #pragma unroll
    for (int q=0;q<4;++q) {
      int cc = c4 + q;
      hv[q] = w_init[cc*3+0]*xm2 + w_init[cc*3+1]*xm1 + w_init[cc*3+2]*x0 + b_init[cc];
    }
    unsigned p0 = pack2(hv[0],hv[1]), p1 = pack2(hv[2],hv[3]);
    unsigned int* hb = (unsigned int*)&h_h16[(size_t)t*512 + c4];
    hb[0] = p0; hb[1] = p1;
    unsigned int* sb = (unsigned int*)&S[r][c4];
    sb[0] = p0; sb[1] = p1;
  }
  __syncthreads();

  const int w = tid >> 6, l = tid & 63, lr = l & 15, lc = l >> 4;
  f32x4 acc[2][4];
  #pragma unroll
  for (int mf=0;mf<2;++mf)
    #pragma unroll
    for (int nf=0;nf<4;++nf) acc[mf][nf] = {0.f,0.f,0.f,0.f};
  for (int kc=0;kc<512;kc+=32) {
    f16x8 b[4];
    #pragma unroll
    for (int nf=0;nf<4;++nf)
      b[nf] = ldh(&S[16*nf+lr][kc + lc*8]);
    #pragma unroll
    for (int mf=0;mf<2;++mf) {
      f16x8 a = ldh(&Wiskip[(size_t)(w*32+16*mf+lr)*512 + kc + lc*8]);
      #pragma unroll
      for (int nf=0;nf<4;++nf)
        acc[mf][nf] = MFMA16(a, b[nf], acc[mf][nf]);
    }
  }
  #pragma unroll
  for (int mf=0;mf<2;++mf)
    #pragma unroll
    for (int nf=0;nf<4;++nf) {
      int s0 = w*32+16*mf+4*lc;
      int t  = tb+16*nf+lr;
      unsigned int* pp = (unsigned int*)&skip16[(size_t)t*256+s0];
      pp[0] = pack2(acc[mf][nf][0]+b_iskip[s0+0], acc[mf][nf][1]+b_iskip[s0+1]);
      pp[1] = pack2(acc[mf][nf][2]+b_iskip[s0+2], acc[mf][nf][3]+b_iskip[s0+3]);
    }
}

// ---------------- K1: dilated conv + gating (m97 template, BN=256) ----------------
__global__ __launch_bounds__(512, 4) void dil_kernel(
    const unsigned short* __restrict__ h_in,    // [T][512] fp16
    unsigned short* __restrict__ pre,           // [T][512] fp16
    const unsigned short* __restrict__ A_dil,   // [3][1024][512] fp16
    const float* __restrict__ cond,             // [1024][32]
    const unsigned short* __restrict__ zerobuf, // zeros
    int dilation) {
  __shared__ unsigned short Ab[2][128][32];
  __shared__ unsigned short Bb[2][256][32];
  const int tid = threadIdx.x;
  const int w = tid >> 6, l = tid & 63;
  const int lr = l & 15, lc = l >> 4;
  const int nt = blockIdx.x & 63, mt = blockIdx.x >> 6;
  const int tb = nt << 8;
  const int e  = tb >> 9;
  const int wr = w >> 2, wc = w & 3;

  const int srowA = (w<<4) + (l>>2);
  const int srowB0 = (w<<5) + (l>>2);
  const int schunk = (l & 3) << 3;

  f32x4 fa[2][4], ga[2][4];
  #pragma unroll
  for (int mf=0;mf<2;++mf)
    #pragma unroll
    for (int nf=0;nf<4;++nf) { fa[mf][nf] = {0.f,0.f,0.f,0.f}; ga[mf][nf] = {0.f,0.f,0.f,0.f}; }

  auto stage = [&](int buf, int s){
    const int tap = s >> 4;
    const int kc  = (s & 15) << 5;
    const int shift = (2 - tap) * dilation;
    {
      const int r = srowA;
      const int m = mt*64 + r + ((r>>6)*448);
      gll16(A_dil + (size_t)tap*(1024*512) + (size_t)m*512 + kc + schunk,
            &Ab[buf][(w<<4)][0]);
    }
    #pragma unroll
    for (int j=0;j<2;++j){
      const int r = srowB0 + (j<<4);
      const int t = tb + r - shift;
      const unsigned short* srcB = (t >= 0) ? (h_in + (size_t)t*512 + kc + schunk)
                                            : (zerobuf + schunk);
      gll16(srcB, &Bb[buf][(w<<5)+(j<<4)][0]);
    }
  };

  stage(0, 0);
  for (int s=0; s<48; ++s) {
    const int cur = s & 1;
    __syncthreads();
    if (s+1 < 48) stage(cur^1, s+1);
    f16x8 af[2], ag[2], bf[4];
    #pragma unroll
    for (int mf=0;mf<2;++mf){
      const int row = (wr<<5) + (mf<<4) + lr;
      af[mf] = ldh(&Ab[cur][row][lc<<3]);
      ag[mf] = ldh(&Ab[cur][64+row][lc<<3]);
    }
    #pragma unroll
    for (int nf=0;nf<4;++nf)
      bf[nf] = ldh(&Bb[cur][(wc<<6)+(nf<<4)+lr][lc<<3]);
    #pragma unroll
    for (int mf=0;mf<2;++mf)
      #pragma unroll
      for (int nf=0;nf<4;++nf){
        fa[mf][nf] = MFMA16(af[mf], bf[nf], fa[mf][nf]);
        ga[mf][nf] = MFMA16(ag[mf], bf[nf], ga[mf][nf]);
      }
  }

  #pragma unroll
  for (int mf=0;mf<2;++mf)
    #pragma unroll
    for (int nf=0;nf<4;++nf){
      const int m0 = mt*64 + (wr<<5) + (mf<<4) + (lc<<2);
      const int t  = tb + (wc<<6) + (nf<<4) + lr;
      float pv[4];
      #pragma unroll
      for (int r=0;r<4;++r){
        float f = fa[mf][nf][r] + cond[(size_t)(m0+r)*32 + e];
        float g = ga[mf][nf][r] + cond[(size_t)(m0+r+512)*32 + e];
        pv[r] = sigmoidf_(f) * tanhf_(g);
      }
      unsigned int* pp = (unsigned int*)&pre[(size_t)t*512 + m0];
      pp[0] = pack2(pv[0], pv[1]);
      pp[1] = pack2(pv[2], pv[3]);
    }
}

// ---------------- K2: res + skip GEMMs (BN=256, M=128 tiles) ----------------
__global__ __launch_bounds__(512, 4) void ressk_kernel(
    const unsigned short* __restrict__ pre,
    const unsigned short* __restrict__ h_in,
    unsigned short* __restrict__ h_out,
    unsigned short* __restrict__ skip16,
    const unsigned short* __restrict__ Wres,
    const unsigned short* __restrict__ Wskip,
    const float* __restrict__ b_res,
    const float* __restrict__ b_skip) {
  __shared__ unsigned short Ab[2][128][32];
  __shared__ unsigned short Bb[2][256][32];
  const int tid = threadIdx.x;
  const int w = tid >> 6, l = tid & 63;
  const int lr = l & 15, lc = l >> 4;
  const int nt = blockIdx.x & 63, mt = blockIdx.x >> 6;
  const int tb = nt << 8;
  const int wr = w >> 2, wc = w & 3;
  const bool isres = (mt < 4);
  const unsigned short* W = isres ? Wres : Wskip;
  const int mrow0 = (isres ? mt : (mt-4)) * 128;

  const int srowA = (w<<4) + (l>>2);
  const int srowB0 = (w<<5) + (l>>2);
  const int schunk = (l & 3) << 3;

  f32x4 acc[4][4];
  #pragma unroll
  for (int mf=0;mf<4;++mf)
    #pragma unroll
    for (int nf=0;nf<4;++nf) acc[mf][nf] = {0.f,0.f,0.f,0.f};

  auto stage = [&](int buf, int s){
    const int kc = s << 5;
    gll16(W + (size_t)(mrow0 + srowA)*512 + kc + schunk, &Ab[buf][(w<<4)][0]);
    #pragma unroll
    for (int j=0;j<2;++j){
      const int r = srowB0 + (j<<4);
      gll16(pre + (size_t)(tb + r)*512 + kc + schunk, &Bb[buf][(w<<5)+(j<<4)][0]);
    }
  };

  stage(0, 0);
  for (int s=0; s<16; ++s) {
    const int cur = s & 1;
    __syncthreads();
    if (s+1 < 16) stage(cur^1, s+1);
    f16x8 a[4], bf[4];
    #pragma unroll
    for (int mf=0;mf<4;++mf)
      a[mf] = ldh(&Ab[cur][(wr<<6)+(mf<<4)+lr][lc<<3]);
    #pragma unroll
    for (int nf=0;nf<4;++nf)
      bf[nf] = ldh(&Bb[cur][(wc<<6)+(nf<<4)+lr][lc<<3]);
    #pragma unroll
    for (int mf=0;mf<4;++mf)
      #pragma unroll
      for (int nf=0;nf<4;++nf)
        acc[mf][nf] = MFMA16(a[mf], bf[nf], acc[mf][nf]);
  }

  if (isres) {
    #pragma unroll
    for (int mf=0;mf<4;++mf)
      #pragma unroll
      for (int nf=0;nf<4;++nf){
        const int m0 = mrow0 + (wr<<6) + (mf<<4) + (lc<<2);
        const int t  = tb + (wc<<6) + (nf<<4) + lr;
        const unsigned int* hi = (const unsigned int*)&h_in[(size_t)t*512 + m0];
        unsigned int h01 = hi[0], h23 = hi[1];
        float v0 = uplo(h01) + acc[mf][nf][0] + b_res[m0+0];
        float v1 = uphi(h01) + acc[mf][nf][1] + b_res[m0+1];
        float v2 = uplo(h23) + acc[mf][nf][2] + b_res[m0+2];
        float v3 = uphi(h23) + acc[mf][nf][3] + b_res[m0+3];
        unsigned int* hb = (unsigned int*)&h_out[(size_t)t*512 + m0];
        hb[0] = pack2(v0,v1); hb[1] = pack2(v2,v3);
      }
  } else {
    #pragma unroll
    for (int mf=0;mf<4;++mf)
      #pragma unroll
      for (int nf=0;nf<4;++nf){
        const int s0 = mrow0 + (wr<<6) + (mf<<4) + (lc<<2);
        const int t  = tb + (wc<<6) + (nf<<4) + lr;
        unsigned int* sp = (unsigned int*)&skip16[(size_t)t*256 + s0];
        unsigned int s01 = sp[0], s23 = sp[1];
        float v0 = uplo(s01) + acc[mf][nf][0] + b_skip[s0+0];
        float v1 = uphi(s01) + acc[mf][nf][1] + b_skip[s0+1];
        float v2 = uplo(s23) + acc[mf][nf][2] + b_skip[s0+2];
        float v3 = uphi(s23) + acc[mf][nf][3] + b_skip[s0+3];
        sp[0] = pack2(v0,v1); sp[1] = pack2(v2,v3);
      }
  }
}

// ---------------- final head ----------------
__global__ __launch_bounds__(512) void final_kernel(
    const unsigned short* __restrict__ skip16, const unsigned short* __restrict__ Wfs,
    const float* __restrict__ b_fskip, const float* __restrict__ fcond,
    const unsigned short* __restrict__ Wq, const float* __restrict__ b_quant,
    float* __restrict__ out) {
  __shared__ unsigned short S1[64][264];
  __shared__ unsigned short S2[64][264];
  int tid=threadIdx.x, w=tid>>6, l=tid&63, lr=l&15, lc=l>>4;
  int tb = blockIdx.x<<6, e = tb>>9;

  for (int j = tid; j < 64*32; j += 512) {
    int r  = j >> 5;
    int c8 = (j & 31) << 3;
    const unsigned int* sp = (const unsigned int*)&skip16[(size_t)(tb+r)*256 + c8];
    unsigned int* dp = (unsigned int*)&S1[r][c8];
    #pragma unroll
    for (int q=0;q<4;++q){
      unsigned int u = sp[q];
      dp[q] = pack2(fmaxf(uplo(u),0.f), fmaxf(uphi(u),0.f));
    }
  }
  __syncthreads();

  f32x4 acc[2][4];
  #pragma unroll
  for (int mf=0;mf<2;++mf)
    #pragma unroll
    for (int nf=0;nf<4;++nf) acc[mf][nf] = {0.f,0.f,0.f,0.f};
  for (int kc=0;kc<256;kc+=32) {
    f16x8 b[4];
    #pragma unroll
    for (int nf=0;nf<4;++nf) b[nf] = ldh(&S1[16*nf+lr][kc + lc*8]);
    #pragma unroll
    for (int mf=0;mf<2;++mf) {
      f16x8 a = ldh(&Wfs[(size_t)(w*32+16*mf+lr)*256 + kc + lc*8]);
      #pragma unroll
      for (int nf=0;nf<4;++nf)
        acc[mf][nf] = MFMA16(a, b[nf], acc[mf][nf]);
    }
  }
  #pragma unroll
  for (int mf=0;mf<2;++mf)
    #pragma unroll
    for (int nf=0;nf<4;++nf) {
      int m0 = w*32+16*mf+4*lc;
      int n  = 16*nf+lr;
      float pv[4];
      #pragma unroll
      for (int r=0;r<4;++r) {
        float v = acc[mf][nf][r] + b_fskip[m0+r] + fcond[(size_t)(m0+r)*32 + e];
        pv[r] = fmaxf(v, 0.f);
      }
      unsigned int* pp = (unsigned int*)&S2[n][m0];
      pp[0] = pack2(pv[0],pv[1]); pp[1] = pack2(pv[2],pv[3]);
    }
  __syncthreads();

  f32x4 acc2[2][4];
  #pragma unroll
  for (int mf=0;mf<2;++mf)
    #pragma unroll
    for (int nf=0;nf<4;++nf) acc2[mf][nf] = {0.f,0.f,0.f,0.f};
  for (int kc=0;kc<256;kc+=32) {
    f16x8 b[4];
    #pragma unroll
    for (int nf=0;nf<4;++nf) b[nf] = ldh(&S2[16*nf+lr][kc + lc*8]);
    #pragma unroll
    for (int mf=0;mf<2;++mf) {
      f16x8 a = ldh(&Wq[(size_t)(w*32+16*mf+lr)*256 + kc + lc*8]);
      #pragma unroll
      for (int nf=0;nf<4;++nf)
        acc2[mf][nf] = MFMA16(a, b[nf], acc2[mf][nf]);
    }
  }
  #pragma unroll
  for (int mf=0;mf<2;++mf)
    #pragma unroll
    for (int nf=0;nf<4;++nf) {
      int q0 = w*32+16*mf+4*lc;
      int t  = tb + 16*nf + lr;
      #pragma unroll
      for (int r=0;r<4;++r)
        out[(size_t)(q0+r)*TLEN + t] = acc2[mf][nf][r] + b_quant[q0+r];
    }
}

// ---------------- host ----------------

extern "C" void kernel_launch(void* const* d_in, const int* in_sizes, int n_in,
                              void* d_out, int out_size, void* d_ws, size_t ws_size,
                              hipStream_t stream) {
  const float* x       = (const float*)d_in[0];
  const float* emb     = (const float*)d_in[1];
  const float* w_init  = (const float*)d_in[2];
  const float* b_init  = (const float*)d_in[3];
  const float* w_iskip = (const float*)d_in[4];
  const float* b_iskip = (const float*)d_in[5];
  const float* w_dil   = (const float*)d_in[6];
  const float* b_dil   = (const float*)d_in[7];
  const float* w_cond  = (const float*)d_in[8];
  const float* b_cond  = (const float*)d_in[9];
  const float* w_res   = (const float*)d_in[10];
  const float* b_res   = (const float*)d_in[11];
  const float* w_skip  = (const float*)d_in[12];
  const float* b_skip  = (const float*)d_in[13];
  const float* w_fskip = (const float*)d_in[14];
  const float* b_fskip = (const float*)d_in[15];
  const float* w_fcond = (const float*)d_in[16];
  const float* b_fcond = (const float*)d_in[17];
  const float* w_quant = (const float*)d_in[18];
  const float* b_quant = (const float*)d_in[19];
  float* out = (float*)d_out;

  char* ws = (char*)d_ws;
  size_t off = 0;
  auto carve = [&](size_t bytes) -> void* {
    void* p = ws + off;
    off += (bytes + 255) & ~(size_t)255;
    return p;
  };
  unsigned short* A_dil     = (unsigned short*)carve((size_t)NSTACK*3*1024*512*2);
  unsigned short* Wres_h    = (unsigned short*)carve((size_t)NSTACK*512*512*2);
  unsigned short* Wskip_h   = (unsigned short*)carve((size_t)NSTACK*256*512*2);
  unsigned short* Wiskip_h  = (unsigned short*)carve((size_t)256*512*2);
  unsigned short* Wfskip_h  = (unsigned short*)carve((size_t)256*256*2);
  unsigned short* Wquant_h  = (unsigned short*)carve((size_t)256*256*2);
  unsigned short* h_h16     = (unsigned short*)carve((size_t)2*TLEN*512*2);
  unsigned short* pre_h16   = (unsigned short*)carve((size_t)TLEN*512*2);
  unsigned short* skip_h16  = (unsigned short*)carve((size_t)TLEN*256*2);
  float*          cond_all  = (float*)carve((size_t)NSTACK*1024*32*4);
  float*          fcond_all = (float*)carve((size_t)256*32*4);
  unsigned short* zerobuf   = (unsigned short*)carve((size_t)512*2);
  if (off > ws_size) return;

  hipMemsetAsync(zerobuf, 0, 512*2, stream);

  prep_kernel<<<(int)(PREP_TOTAL/256), 256, 0, stream>>>(
      w_dil, A_dil, w_res, Wres_h, w_skip, Wskip_h, w_iskip, Wiskip_h,
      w_fskip, Wfskip_h, w_quant, Wquant_h,
      emb, w_cond, b_cond, b_dil, w_fcond, b_fcond, cond_all, fcond_all);

  hs_kernel<<<TLEN/64, 512, 0, stream>>>(
      x, w_init, b_init, h_h16, Wiskip_h, b_iskip, skip_h16);

  const size_t HB = (size_t)TLEN*512;
  for (int i = 0; i < NSTACK; ++i) {
    int d = 1 << (i % 10);
    const unsigned short* h_in = h_h16 + (size_t)(i & 1)*HB;
    unsigned short* h_out      = h_h16 + (size_t)((i + 1) & 1)*HB;
    dil_kernel<<<512, 512, 0, stream>>>(
        h_in,
        pre_h16,
        A_dil + (size_t)i*3*1024*512,
        cond_all + (size_t)i*1024*32,
        zerobuf,
        d);
    ressk_kernel<<<384, 512, 0, stream>>>(
        pre_h16,
        h_in,
        h_out,
        skip_h16,
        Wres_h + (size_t)i*512*512,
        Wskip_h + (size_t)i*256*512,
        b_res + (size_t)i*512,
        b_skip + (size_t)i*256);
  }

  final_kernel<<<TLEN/64, 512, 0, stream>>>(
      skip_h16, Wfskip_h, b_fskip, fcond_all, Wquant_h, b_quant, out);
}

// Round 18
// 2819.473 us; speedup vs baseline: 2.2613x; 1.0338x over previous
//
#include <hip/hip_runtime.h>

// WaveNet decoder for MI355X (gfx950) — round-17 base (best 2.91ms) +
// tap-overlap B-reuse in dil for d<=64 (21/30 layers): one widened B tile
// [tb-128, tb+256) staged ONCE per k-chunk serves all 3 taps (read at LDS row
// 128+col-shift). Staging 3->2 gll/wave/step; B global traffic halved.
// d>64 layers use the unchanged dil_kernel (separate function, no regalloc merge).

typedef _Float16 f16x8 __attribute__((ext_vector_type(8)));
typedef float f32x4 __attribute__((ext_vector_type(4)));

#define NSTACK 30
#define TLEN   16384

typedef __attribute__((address_space(1))) const unsigned int glob_u32;
typedef __attribute__((address_space(3))) unsigned int lds_u32;

__device__ __forceinline__ void gll16(const unsigned short* g, unsigned short* l) {
  __builtin_amdgcn_global_load_lds((glob_u32*)g, (lds_u32*)l, 16, 0, 0);
}

__device__ __forceinline__ unsigned short f2h(float x) {
  union { _Float16 h; unsigned short u; } c;
  c.h = (_Float16)x;
  return c.u;
}
__device__ __forceinline__ unsigned pack2(float a, float b) {
  return (unsigned)f2h(a) | ((unsigned)f2h(b) << 16);
}
__device__ __forceinline__ float uplo(unsigned u){ union{unsigned v;_Float16 h[2];}c; c.v=u; return (float)c.h[0]; }
__device__ __forceinline__ float uphi(unsigned u){ union{unsigned v;_Float16 h[2];}c; c.v=u; return (float)c.h[1]; }
__device__ __forceinline__ f16x8 ldh(const unsigned short* p) {
  return *(const f16x8*)p;
}
__device__ __forceinline__ float sigmoidf_(float x){ return 1.0f/(1.0f+__expf(-x)); }
__device__ __forceinline__ float tanhf_(float x){ return 1.0f - 2.0f/(__expf(2.0f*x)+1.0f); }
#define MFMA16(a,b,c) __builtin_amdgcn_mfma_f32_16x16x32_f16((a),(b),(c),0,0,0)

// ---------------- fused prep kernel ----------------
#define SEG_T  15728640L
#define SEG_R  1966080L
#define SEG_S  983040L
#define SEG_I  32768L
#define SEG_F  16384L
#define SEG_Q  16384L
#define SEG_C  30976L
#define PREP_TOTAL (SEG_T+SEG_R+SEG_S+SEG_I+SEG_F+SEG_Q+SEG_C)

__device__ __forceinline__ void cast4(const float* src, unsigned short* dst, long g){
  f32x4 v = *(const f32x4*)(src + 4*g);
  unsigned int* d = (unsigned int*)(dst + 4*g);
  d[0] = pack2(v[0], v[1]);
  d[1] = pack2(v[2], v[3]);
}

__global__ void prep_kernel(
    const float* __restrict__ w_dil,  unsigned short* __restrict__ A_dil,
    const float* __restrict__ w_res,  unsigned short* __restrict__ Wres_h,
    const float* __restrict__ w_skip, unsigned short* __restrict__ Wskip_h,
    const float* __restrict__ w_iskip,unsigned short* __restrict__ Wiskip_h,
    const float* __restrict__ w_fskip,unsigned short* __restrict__ Wfskip_h,
    const float* __restrict__ w_quant,unsigned short* __restrict__ Wquant_h,
    const float* __restrict__ emb,
    const float* __restrict__ w_cond, const float* __restrict__ b_cond,
    const float* __restrict__ b_dil,
    const float* __restrict__ w_fcond,const float* __restrict__ b_fcond,
    float* __restrict__ cond_all, float* __restrict__ fcond_all) {
  long g = (long)blockIdx.x*256 + threadIdx.x;
  if (g < SEG_T) {
    int c = (int)(g & 511);
    int m = (int)((g >> 9) & 1023);
    int i = (int)(g >> 19);
    const float* s = w_dil + g*3;
    #pragma unroll
    for (int tap=0; tap<3; ++tap)
      A_dil[(((size_t)i*3+tap)*1024 + m)*512 + c] = f2h(s[tap]);
    return;
  }
  g -= SEG_T;
  if (g < SEG_R) { cast4(w_res,  Wres_h,  g); return; }
  g -= SEG_R;
  if (g < SEG_S) { cast4(w_skip, Wskip_h, g); return; }
  g -= SEG_S;
  if (g < SEG_I) { cast4(w_iskip, Wiskip_h, g); return; }
  g -= SEG_I;
  if (g < SEG_F) { cast4(w_fskip, Wfskip_h, g); return; }
  g -= SEG_F;
  if (g < SEG_Q) { cast4(w_quant, Wquant_h, g); return; }
  g -= SEG_Q;
  if (g < NSTACK*1024) {
    int row = (int)g;
    float acc[32];
    float base = b_cond[row] + b_dil[row];
    #pragma unroll
    for (int e=0;e<32;++e) acc[e] = base;
    #pragma unroll
    for (int c=0;c<16;++c) {
      float wv = w_cond[(size_t)row*16 + c];
      #pragma unroll
      for (int e=0;e<32;++e) acc[e] += wv * emb[c*32+e];
    }
    #pragma unroll
    for (int e=0;e<32;++e) cond_all[(size_t)row*32+e] = acc[e];
  } else if (g < NSTACK*1024 + 256) {
    int m = (int)(g - NSTACK*1024);
    float acc[32];
    float base = b_fcond[m];
    #pragma unroll
    for (int c=0;c<16;++c) {
      float wv = w_fcond[(size_t)m*16 + c];
      #pragma unroll
      for (int e=0;e<32;++e) acc[e] = (c==0 ? base : acc[e]) + wv * emb[c*32+e];
    }
    #pragma unroll
    for (int e=0;e<32;++e) fcond_all[(size_t)m*32+e] = acc[e];
  }
}

// ---------------- fused h0 + skip_init ----------------
__global__ __launch_bounds__(512) void hs_kernel(
    const float* __restrict__ x, const float* __restrict__ w_init,
    const float* __restrict__ b_init,
    unsigned short* __restrict__ h_h16,
    const unsigned short* __restrict__ Wiskip,
    const float* __restrict__ b_iskip, unsigned short* __restrict__ skip16) {
  __shared__ unsigned short S[64][520];
  const int tid = threadIdx.x;
  const int tb = blockIdx.x << 6;

  for (int j = tid; j < 64*128; j += 512) {
    int r  = j >> 7;
    int c4 = (j & 127) << 2;
    int t  = tb + r;
    float xm2 = (t>=2)? x[t-2] : 0.f;
    float xm1 = (t>=1)? x[t-1] : 0.f;
    float x0  = x[t];
    float hv[4];
    #pragma unroll
    for (int q=0;q<4;++q) {
      int cc = c4 + q;
      hv[q] = w_init[cc*3+0]*xm2 + w_init[cc*3+1]*xm1 + w_init[cc*3+2]*x0 + b_init[cc];
    }
    unsigned p0 = pack2(hv[0],hv[1]), p1 = pack2(hv[2],hv[3]);
    unsigned int* hb = (unsigned int*)&h_h16[(size_t)t*512 + c4];
    hb[0] = p0; hb[1] = p1;
    unsigned int* sb = (unsigned int*)&S[r][c4];
    sb[0] = p0; sb[1] = p1;
  }
  __syncthreads();

  const int w = tid >> 6, l = tid & 63, lr = l & 15, lc = l >> 4;
  f32x4 acc[2][4];
  #pragma unroll
  for (int mf=0;mf<2;++mf)
    #pragma unroll
    for (int nf=0;nf<4;++nf) acc[mf][nf] = {0.f,0.f,0.f,0.f};
  for (int kc=0;kc<512;kc+=32) {
    f16x8 b[4];
    #pragma unroll
    for (int nf=0;nf<4;++nf)
      b[nf] = ldh(&S[16*nf+lr][kc + lc*8]);
    #pragma unroll
    for (int mf=0;mf<2;++mf) {
      f16x8 a = ldh(&Wiskip[(size_t)(w*32+16*mf+lr)*512 + kc + lc*8]);
      #pragma unroll
      for (int nf=0;nf<4;++nf)
        acc[mf][nf] = MFMA16(a, b[nf], acc[mf][nf]);
    }
  }
  #pragma unroll
  for (int mf=0;mf<2;++mf)
    #pragma unroll
    for (int nf=0;nf<4;++nf) {
      int s0 = w*32+16*mf+4*lc;
      int t  = tb+16*nf+lr;
      unsigned int* pp = (unsigned int*)&skip16[(size_t)t*256+s0];
      pp[0] = pack2(acc[mf][nf][0]+b_iskip[s0+0], acc[mf][nf][1]+b_iskip[s0+1]);
      pp[1] = pack2(acc[mf][nf][2]+b_iskip[s0+2], acc[mf][nf][3]+b_iskip[s0+3]);
    }
}

// ---------------- K1a: dil for d<=64 (tap-overlap B-reuse) ----------------
// grid = 512: nt = bid&63 (t-tile of 256), mt = bid>>6.
// B tile: 384 rows = h[tb-128, tb+256), staged ONCE per k-chunk (3 gll/wave).
// A: 128 rows per (kc,tap), staged per step (1 gll/wave). 48 steps (16 kc x 3 tap).
// Tap reads B at LDS row 128 + col - (2-tap)*d. LDS 64KB -> 2 blocks/CU.
__global__ __launch_bounds__(512, 4) void dil_small_kernel(
    const unsigned short* __restrict__ h_in,
    unsigned short* __restrict__ pre,
    const unsigned short* __restrict__ A_dil,
    const float* __restrict__ cond,
    const unsigned short* __restrict__ zerobuf,
    int dilation) {                              // dilation <= 64
  __shared__ unsigned short Ab[2][128][32];
  __shared__ unsigned short Bb[2][384][32];
  const int tid = threadIdx.x;
  const int w = tid >> 6, l = tid & 63;
  const int lr = l & 15, lc = l >> 4;
  const int nt = blockIdx.x & 63, mt = blockIdx.x >> 6;
  const int tb = nt << 8;
  const int e  = tb >> 9;
  const int wr = w >> 2, wc = w & 3;

  const int srowA  = (w<<4) + (l>>2);          // A: 16 rows/wave
  const int srowB0 = w*48 + (l>>2);            // B: 48 rows/wave (3 gll)
  const int schunk = (l & 3) << 3;

  f32x4 fa[2][4], ga[2][4];
  #pragma unroll
  for (int mf=0;mf<2;++mf)
    #pragma unroll
    for (int nf=0;nf<4;++nf) { fa[mf][nf] = {0.f,0.f,0.f,0.f}; ga[mf][nf] = {0.f,0.f,0.f,0.f}; }

  auto stageA = [&](int buf, int s){
    const int kcc = s / 3;
    const int tap = s - kcc*3;
    const int kc  = kcc << 5;
    const int r = srowA;
    const int m = mt*64 + r + ((r>>6)*448);    // r<64: filter ; r>=64: gate+512
    gll16(A_dil + (size_t)tap*(1024*512) + (size_t)m*512 + kc + schunk,
          &Ab[buf][(w<<4)][0]);
  };
  auto stageB = [&](int buf, int kcc){
    const int kc = kcc << 5;
    #pragma unroll
    for (int j=0;j<3;++j){
      const int r = srowB0 + j*16;
      const int t = tb + r - 128;
      const unsigned short* src = (t >= 0) ? (h_in + (size_t)t*512 + kc + schunk)
                                           : (zerobuf + schunk);
      gll16(src, &Bb[buf][w*48 + j*16][0]);
    }
  };

  stageA(0, 0);
  stageB(0, 0);
  for (int s=0; s<48; ++s) {
    const int curA = s & 1;
    const int kcc = s / 3;
    const int tap = s - kcc*3;
    const int curB = kcc & 1;
    __syncthreads();
    if (s+1 < 48) stageA(curA^1, s+1);
    if (tap == 2 && kcc+1 < 16) stageB(curB^1, kcc+1);
    const int shift = (2 - tap) * dilation;
    f16x8 af[2], ag[2], bf[4];
    #pragma unroll
    for (int mf=0;mf<2;++mf){
      const int row = (wr<<5) + (mf<<4) + lr;
      af[mf] = ldh(&Ab[curA][row][lc<<3]);
      ag[mf] = ldh(&Ab[curA][64+row][lc<<3]);
    }
    #pragma unroll
    for (int nf=0;nf<4;++nf){
      const int col = (wc<<6) + (nf<<4) + lr;
      bf[nf] = ldh(&Bb[curB][128 + col - shift][lc<<3]);
    }
    #pragma unroll
    for (int mf=0;mf<2;++mf)
      #pragma unroll
      for (int nf=0;nf<4;++nf){
        fa[mf][nf] = MFMA16(af[mf], bf[nf], fa[mf][nf]);
        ga[mf][nf] = MFMA16(ag[mf], bf[nf], ga[mf][nf]);
      }
  }

  #pragma unroll
  for (int mf=0;mf<2;++mf)
    #pragma unroll
    for (int nf=0;nf<4;++nf){
      const int m0 = mt*64 + (wr<<5) + (mf<<4) + (lc<<2);
      const int t  = tb + (wc<<6) + (nf<<4) + lr;
      float pv[4];
      #pragma unroll
      for (int r=0;r<4;++r){
        float f = fa[mf][nf][r] + cond[(size_t)(m0+r)*32 + e];
        float g = ga[mf][nf][r] + cond[(size_t)(m0+r+512)*32 + e];
        pv[r] = sigmoidf_(f) * tanhf_(g);
      }
      unsigned int* pp = (unsigned int*)&pre[(size_t)t*512 + m0];
      pp[0] = pack2(pv[0], pv[1]);
      pp[1] = pack2(pv[2], pv[3]);
    }
}

// ---------------- K1b: dil for d>64 (per-tap B staging, round-16 body) ----------------
__global__ __launch_bounds__(512, 4) void dil_kernel(
    const unsigned short* __restrict__ h_in,
    unsigned short* __restrict__ pre,
    const unsigned short* __restrict__ A_dil,
    const float* __restrict__ cond,
    const unsigned short* __restrict__ zerobuf,
    int dilation) {
  __shared__ unsigned short Ab[2][128][32];
  __shared__ unsigned short Bb[2][256][32];
  const int tid = threadIdx.x;
  const int w = tid >> 6, l = tid & 63;
  const int lr = l & 15, lc = l >> 4;
  const int nt = blockIdx.x & 63, mt = blockIdx.x >> 6;
  const int tb = nt << 8;
  const int e  = tb >> 9;
  const int wr = w >> 2, wc = w & 3;

  const int srowA = (w<<4) + (l>>2);
  const int srowB0 = (w<<5) + (l>>2);
  const int schunk = (l & 3) << 3;

  f32x4 fa[2][4], ga[2][4];
  #pragma unroll
  for (int mf=0;mf<2;++mf)
    #pragma unroll
    for (int nf=0;nf<4;++nf) { fa[mf][nf] = {0.f,0.f,0.f,0.f}; ga[mf][nf] = {0.f,0.f,0.f,0.f}; }

  auto stage = [&](int buf, int s){
    const int tap = s >> 4;
    const int kc  = (s & 15) << 5;
    const int shift = (2 - tap) * dilation;
    {
      const int r = srowA;
      const int m = mt*64 + r + ((r>>6)*448);
      gll16(A_dil + (size_t)tap*(1024*512) + (size_t)m*512 + kc + schunk,
            &Ab[buf][(w<<4)][0]);
    }
    #pragma unroll
    for (int j=0;j<2;++j){
      const int r = srowB0 + (j<<4);
      const int t = tb + r - shift;
      const unsigned short* srcB = (t >= 0) ? (h_in + (size_t)t*512 + kc + schunk)
                                            : (zerobuf + schunk);
      gll16(srcB, &Bb[buf][(w<<5)+(j<<4)][0]);
    }
  };

  stage(0, 0);
  for (int s=0; s<48; ++s) {
    const int cur = s & 1;
    __syncthreads();
    if (s+1 < 48) stage(cur^1, s+1);
    f16x8 af[2], ag[2], bf[4];
    #pragma unroll
    for (int mf=0;mf<2;++mf){
      const int row = (wr<<5) + (mf<<4) + lr;
      af[mf] = ldh(&Ab[cur][row][lc<<3]);
      ag[mf] = ldh(&Ab[cur][64+row][lc<<3]);
    }
    #pragma unroll
    for (int nf=0;nf<4;++nf)
      bf[nf] = ldh(&Bb[cur][(wc<<6)+(nf<<4)+lr][lc<<3]);
    #pragma unroll
    for (int mf=0;mf<2;++mf)
      #pragma unroll
      for (int nf=0;nf<4;++nf){
        fa[mf][nf] = MFMA16(af[mf], bf[nf], fa[mf][nf]);
        ga[mf][nf] = MFMA16(ag[mf], bf[nf], ga[mf][nf]);
      }
  }

  #pragma unroll
  for (int mf=0;mf<2;++mf)
    #pragma unroll
    for (int nf=0;nf<4;++nf){
      const int m0 = mt*64 + (wr<<5) + (mf<<4) + (lc<<2);
      const int t  = tb + (wc<<6) + (nf<<4) + lr;
      float pv[4];
      #pragma unroll
      for (int r=0;r<4;++r){
        float f = fa[mf][nf][r] + cond[(size_t)(m0+r)*32 + e];
        float g = ga[mf][nf][r] + cond[(size_t)(m0+r+512)*32 + e];
        pv[r] = sigmoidf_(f) * tanhf_(g);
      }
      unsigned int* pp = (unsigned int*)&pre[(size_t)t*512 + m0];
      pp[0] = pack2(pv[0], pv[1]);
      pp[1] = pack2(pv[2], pv[3]);
    }
}

// ---------------- K2: res + skip GEMMs (BN=256, M=128 tiles) ----------------
__global__ __launch_bounds__(512, 4) void ressk_kernel(
    const unsigned short* __restrict__ pre,
    const unsigned short* __restrict__ h_in,
    unsigned short* __restrict__ h_out,
    unsigned short* __restrict__ skip16,
    const unsigned short* __restrict__ Wres,
    const unsigned short* __restrict__ Wskip,
    const float* __restrict__ b_res,
    const float* __restrict__ b_skip) {
  __shared__ unsigned short Ab[2][128][32];
  __shared__ unsigned short Bb[2][256][32];
  const int tid = threadIdx.x;
  const int w = tid >> 6, l = tid & 63;
  const int lr = l & 15, lc = l >> 4;
  const int nt = blockIdx.x & 63, mt = blockIdx.x >> 6;
  const int tb = nt << 8;
  const int wr = w >> 2, wc = w & 3;
  const bool isres = (mt < 4);
  const unsigned short* W = isres ? Wres : Wskip;
  const int mrow0 = (isres ? mt : (mt-4)) * 128;

  const int srowA = (w<<4) + (l>>2);
  const int srowB0 = (w<<5) + (l>>2);
  const int schunk = (l & 3) << 3;

  f32x4 acc[4][4];
  #pragma unroll
  for (int mf=0;mf<4;++mf)
    #pragma unroll
    for (int nf=0;nf<4;++nf) acc[mf][nf] = {0.f,0.f,0.f,0.f};

  auto stage = [&](int buf, int s){
    const int kc = s << 5;
    gll16(W + (size_t)(mrow0 + srowA)*512 + kc + schunk, &Ab[buf][(w<<4)][0]);
    #pragma unroll
    for (int j=0;j<2;++j){
      const int r = srowB0 + (j<<4);
      gll16(pre + (size_t)(tb + r)*512 + kc + schunk, &Bb[buf][(w<<5)+(j<<4)][0]);
    }
  };

  stage(0, 0);
  for (int s=0; s<16; ++s) {
    const int cur = s & 1;
    __syncthreads();
    if (s+1 < 16) stage(cur^1, s+1);
    f16x8 a[4], bf[4];
    #pragma unroll
    for (int mf=0;mf<4;++mf)
      a[mf] = ldh(&Ab[cur][(wr<<6)+(mf<<4)+lr][lc<<3]);
    #pragma unroll
    for (int nf=0;nf<4;++nf)
      bf[nf] = ldh(&Bb[cur][(wc<<6)+(nf<<4)+lr][lc<<3]);
    #pragma unroll
    for (int mf=0;mf<4;++mf)
      #pragma unroll
      for (int nf=0;nf<4;++nf)
        acc[mf][nf] = MFMA16(a[mf], bf[nf], acc[mf][nf]);
  }

  if (isres) {
    #pragma unroll
    for (int mf=0;mf<4;++mf)
      #pragma unroll
      for (int nf=0;nf<4;++nf){
        const int m0 = mrow0 + (wr<<6) + (mf<<4) + (lc<<2);
        const int t  = tb + (wc<<6) + (nf<<4) + lr;
        const unsigned int* hi = (const unsigned int*)&h_in[(size_t)t*512 + m0];
        unsigned int h01 = hi[0], h23 = hi[1];
        float v0 = uplo(h01) + acc[mf][nf][0] + b_res[m0+0];
        float v1 = uphi(h01) + acc[mf][nf][1] + b_res[m0+1];
        float v2 = uplo(h23) + acc[mf][nf][2] + b_res[m0+2];
        float v3 = uphi(h23) + acc[mf][nf][3] + b_res[m0+3];
        unsigned int* hb = (unsigned int*)&h_out[(size_t)t*512 + m0];
        hb[0] = pack2(v0,v1); hb[1] = pack2(v2,v3);
      }
  } else {
    #pragma unroll
    for (int mf=0;mf<4;++mf)
      #pragma unroll
      for (int nf=0;nf<4;++nf){
        const int s0 = mrow0 + (wr<<6) + (mf<<4) + (lc<<2);
        const int t  = tb + (wc<<6) + (nf<<4) + lr;
        unsigned int* sp = (unsigned int*)&skip16[(size_t)t*256 + s0];
        unsigned int s01 = sp[0], s23 = sp[1];
        float v0 = uplo(s01) + acc[mf][nf][0] + b_skip[s0+0];
        float v1 = uphi(s01) + acc[mf][nf][1] + b_skip[s0+1];
        float v2 = uplo(s23) + acc[mf][nf][2] + b_skip[s0+2];
        float v3 = uphi(s23) + acc[mf][nf][3] + b_skip[s0+3];
        sp[0] = pack2(v0,v1); sp[1] = pack2(v2,v3);
      }
  }
}

// ---------------- final head ----------------
__global__ __launch_bounds__(512) void final_kernel(
    const unsigned short* __restrict__ skip16, const unsigned short* __restrict__ Wfs,
    const float* __restrict__ b_fskip, const float* __restrict__ fcond,
    const unsigned short* __restrict__ Wq, const float* __restrict__ b_quant,
    float* __restrict__ out) {
  __shared__ unsigned short S1[64][264];
  __shared__ unsigned short S2[64][264];
  int tid=threadIdx.x, w=tid>>6, l=tid&63, lr=l&15, lc=l>>4;
  int tb = blockIdx.x<<6, e = tb>>9;

  for (int j = tid; j < 64*32; j += 512) {
    int r  = j >> 5;
    int c8 = (j & 31) << 3;
    const unsigned int* sp = (const unsigned int*)&skip16[(size_t)(tb+r)*256 + c8];
    unsigned int* dp = (unsigned int*)&S1[r][c8];
    #pragma unroll
    for (int q=0;q<4;++q){
      unsigned int u = sp[q];
      dp[q] = pack2(fmaxf(uplo(u),0.f), fmaxf(uphi(u),0.f));
    }
  }
  __syncthreads();

  f32x4 acc[2][4];
  #pragma unroll
  for (int mf=0;mf<2;++mf)
    #pragma unroll
    for (int nf=0;nf<4;++nf) acc[mf][nf] = {0.f,0.f,0.f,0.f};
  for (int kc=0;kc<256;kc+=32) {
    f16x8 b[4];
    #pragma unroll
    for (int nf=0;nf<4;++nf) b[nf] = ldh(&S1[16*nf+lr][kc + lc*8]);
    #pragma unroll
    for (int mf=0;mf<2;++mf) {
      f16x8 a = ldh(&Wfs[(size_t)(w*32+16*mf+lr)*256 + kc + lc*8]);
      #pragma unroll
      for (int nf=0;nf<4;++nf)
        acc[mf][nf] = MFMA16(a, b[nf], acc[mf][nf]);
    }
  }
  #pragma unroll
  for (int mf=0;mf<2;++mf)
    #pragma unroll
    for (int nf=0;nf<4;++nf) {
      int m0 = w*32+16*mf+4*lc;
      int n  = 16*nf+lr;
      float pv[4];
      #pragma unroll
      for (int r=0;r<4;++r) {
        float v = acc[mf][nf][r] + b_fskip[m0+r] + fcond[(size_t)(m0+r)*32 + e];
        pv[r] = fmaxf(v, 0.f);
      }
      unsigned int* pp = (unsigned int*)&S2[n][m0];
      pp[0] = pack2(pv[0],pv[1]); pp[1] = pack2(pv[2],pv[3]);
    }
  __syncthreads();

  f32x4 acc2[2][4];
  #pragma unroll
  for (int mf=0;mf<2;++mf)
    #pragma unroll
    for (int nf=0;nf<4;++nf) acc2[mf][nf] = {0.f,0.f,0.f,0.f};
  for (int kc=0;kc<256;kc+=32) {
    f16x8 b[4];
    #pragma unroll
    for (int nf=0;nf<4;++nf) b[nf] = ldh(&S2[16*nf+lr][kc + lc*8]);
    #pragma unroll
    for (int mf=0;mf<2;++mf) {
      f16x8 a = ldh(&Wq[(size_t)(w*32+16*mf+lr)*256 + kc + lc*8]);
      #pragma unroll
      for (int nf=0;nf<4;++nf)
        acc2[mf][nf] = MFMA16(a, b[nf], acc2[mf][nf]);
    }
  }
  #pragma unroll
  for (int mf=0;mf<2;++mf)
    #pragma unroll
    for (int nf=0;nf<4;++nf) {
      int q0 = w*32+16*mf+4*lc;
      int t  = tb + 16*nf + lr;
      #pragma unroll
      for (int r=0;r<4;++r)
        out[(size_t)(q0+r)*TLEN + t] = acc2[mf][nf][r] + b_quant[q0+r];
    }
}

// ---------------- host ----------------

extern "C" void kernel_launch(void* const* d_in, const int* in_sizes, int n_in,
                              void* d_out, int out_size, void* d_ws, size_t ws_size,
                              hipStream_t stream) {
  const float* x       = (const float*)d_in[0];
  const float* emb     = (const float*)d_in[1];
  const float* w_init  = (const float*)d_in[2];
  const float* b_init  = (const float*)d_in[3];
  const float* w_iskip = (const float*)d_in[4];
  const float* b_iskip = (const float*)d_in[5];
  const float* w_dil   = (const float*)d_in[6];
  const float* b_dil   = (const float*)d_in[7];
  const float* w_cond  = (const float*)d_in[8];
  const float* b_cond  = (const float*)d_in[9];
  const float* w_res   = (const float*)d_in[10];
  const float* b_res   = (const float*)d_in[11];
  const float* w_skip  = (const float*)d_in[12];
  const float* b_skip  = (const float*)d_in[13];
  const float* w_fskip = (const float*)d_in[14];
  const float* b_fskip = (const float*)d_in[15];
  const float* w_fcond = (const float*)d_in[16];
  const float* b_fcond = (const float*)d_in[17];
  const float* w_quant = (const float*)d_in[18];
  const float* b_quant = (const float*)d_in[19];
  float* out = (float*)d_out;

  char* ws = (char*)d_ws;
  size_t off = 0;
  auto carve = [&](size_t bytes) -> void* {
    void* p = ws + off;
    off += (bytes + 255) & ~(size_t)255;
    return p;
  };
  unsigned short* A_dil     = (unsigned short*)carve((size_t)NSTACK*3*1024*512*2);
  unsigned short* Wres_h    = (unsigned short*)carve((size_t)NSTACK*512*512*2);
  unsigned short* Wskip_h   = (unsigned short*)carve((size_t)NSTACK*256*512*2);
  unsigned short* Wiskip_h  = (unsigned short*)carve((size_t)256*512*2);
  unsigned short* Wfskip_h  = (unsigned short*)carve((size_t)256*256*2);
  unsigned short* Wquant_h  = (unsigned short*)carve((size_t)256*256*2);
  unsigned short* h_h16     = (unsigned short*)carve((size_t)2*TLEN*512*2);
  unsigned short* pre_h16   = (unsigned short*)carve((size_t)TLEN*512*2);
  unsigned short* skip_h16  = (unsigned short*)carve((size_t)TLEN*256*2);
  float*          cond_all  = (float*)carve((size_t)NSTACK*1024*32*4);
  float*          fcond_all = (float*)carve((size_t)256*32*4);
  unsigned short* zerobuf   = (unsigned short*)carve((size_t)512*2);
  if (off > ws_size) return;

  hipMemsetAsync(zerobuf, 0, 512*2, stream);

  prep_kernel<<<(int)(PREP_TOTAL/256), 256, 0, stream>>>(
      w_dil, A_dil, w_res, Wres_h, w_skip, Wskip_h, w_iskip, Wiskip_h,
      w_fskip, Wfskip_h, w_quant, Wquant_h,
      emb, w_cond, b_cond, b_dil, w_fcond, b_fcond, cond_all, fcond_all);

  hs_kernel<<<TLEN/64, 512, 0, stream>>>(
      x, w_init, b_init, h_h16, Wiskip_h, b_iskip, skip_h16);

  const size_t HB = (size_t)TLEN*512;
  for (int i = 0; i < NSTACK; ++i) {
    int d = 1 << (i % 10);
    const unsigned short* h_in = h_h16 + (size_t)(i & 1)*HB;
    unsigned short* h_out      = h_h16 + (size_t)((i + 1) & 1)*HB;
    if (d <= 64) {
      dil_small_kernel<<<512, 512, 0, stream>>>(
          h_in, pre_h16,
          A_dil + (size_t)i*3*1024*512,
          cond_all + (size_t)i*1024*32,
          zerobuf, d);
    } else {
      dil_kernel<<<512, 512, 0, stream>>>(
          h_in, pre_h16,
          A_dil + (size_t)i*3*1024*512,
          cond_all + (size_t)i*1024*32,
          zerobuf, d);
    }
    ressk_kernel<<<384, 512, 0, stream>>>(
        pre_h16, h_in, h_out, skip_h16,
        Wres_h + (size_t)i*512*512,
        Wskip_h + (size_t)i*256*512,
        b_res + (size_t)i*512,
        b_skip + (size_t)i*256);
  }

  final_kernel<<<TLEN/64, 512, 0, stream>>>(
      skip_h16, Wfskip_h, b_fskip, fcond_all, Wquant_h, b_quant, out);
}